// Round 6
// baseline (469.189 us; speedup 1.0000x reference)
//
#include <hip/hip_runtime.h>

#define FD 96   // feature dim

// ---------------------------------------------------------------------------
// K1: degree histogram (int counts). Hub handled via ballot+popcount.
// ---------------------------------------------------------------------------
__global__ void deg_kernel(const int* __restrict__ dst, int E, int HUB,
                           int* __restrict__ counts) {
    int e = blockIdx.x * 256 + threadIdx.x;
    int d = (e < E) ? dst[e] : -1;
    bool isHub = (d == HUB);
    unsigned long long m = __ballot(isHub);
    if (isHub) {
        int lane = threadIdx.x & 63;
        if (lane == __ffsll((unsigned long long)m) - 1)
            atomicAdd(&counts[HUB], (int)__popcll(m));
    } else if (d >= 0) {
        atomicAdd(&counts[d], 1);
    }
}

// ---------------------------------------------------------------------------
// K2: exclusive prefix sum of counts -> rowptr[N+1]. Single block.
// ---------------------------------------------------------------------------
__global__ __launch_bounds__(1024)
void scan_kernel(const int* __restrict__ counts, int* __restrict__ rowptr, int N) {
    const int T = 1024;
    int lane = threadIdx.x & 63;
    int wv   = threadIdx.x >> 6;      // 0..15
    __shared__ int wsum[16];
    __shared__ int carry_s;
    if (threadIdx.x == 0) carry_s = 0;
    __syncthreads();
    for (int base = 0; base < N; base += T) {
        int i = base + threadIdx.x;
        int v = (i < N) ? counts[i] : 0;
        int x = v;
        #pragma unroll
        for (int off = 1; off < 64; off <<= 1) {
            int t = __shfl_up(x, off);
            if (lane >= off) x += t;
        }
        if (lane == 63) wsum[wv] = x;
        __syncthreads();
        if (wv == 0 && lane < 16) {
            int w = wsum[lane];
            #pragma unroll
            for (int off = 1; off < 16; off <<= 1) {
                int t = __shfl_up(w, off);
                if (lane >= off) w += t;
            }
            wsum[lane] = w;
        }
        __syncthreads();
        int waveoff = (wv == 0) ? 0 : wsum[wv - 1];
        int carry = carry_s;
        int incl = carry + waveoff + x;
        if (i < N) rowptr[i] = incl - v;       // exclusive
        __syncthreads();
        if (threadIdx.x == T - 1) carry_s = incl;
        __syncthreads();
    }
    if (threadIdx.x == 0) rowptr[N] = carry_s;
}

// ---------------------------------------------------------------------------
// K3: fill CSR col[]. Hub cursor via wave-aggregated atomic.
// ---------------------------------------------------------------------------
__global__ void fill_kernel(const int* __restrict__ src, const int* __restrict__ dst,
                            int E, int HUB, const int* __restrict__ rowptr,
                            int* __restrict__ cursor, int* __restrict__ col) {
    int e = blockIdx.x * 256 + threadIdx.x;
    if (e >= E) return;
    int d = dst[e];
    bool isHub = (d == HUB);
    unsigned long long m = __ballot(isHub);
    int pos;
    if (isHub) {
        int lane = threadIdx.x & 63;
        int leader = __ffsll((unsigned long long)m) - 1;
        int base = 0;
        if (lane == leader) base = atomicAdd(&cursor[HUB], (int)__popcll(m));
        base = __shfl(base, leader);
        unsigned long long below = m & ((1ull << lane) - 1ull);
        pos = base + (int)__popcll(below);
    } else {
        pos = atomicAdd(&cursor[d], 1);
    }
    col[rowptr[d] + pos] = src[e];
}

// ---------------------------------------------------------------------------
// K4: dinv from int counts
// ---------------------------------------------------------------------------
__global__ void dinv_kernel(const int* __restrict__ counts, float* __restrict__ dinv,
                            int N) {
    int n = blockIdx.x * 256 + threadIdx.x;
    if (n < N) {
        float d = (float)counts[n];
        dinv[n] = (d > 0.f) ? rsqrtf(fmaxf(d, 1.f)) : 0.f;
    }
}

// ---------------------------------------------------------------------------
// K5: FUSED pull-aggregation + GEMM (+bias, +relu).
// block (24,16): gather-aggregate 16 rows (8-deep unrolled edge loop for MLP),
// stage rows + W (36 KB) in LDS, then in-block [16x96]@[96x96] GEMM.
// out[n] = act( (dinv[n]*sum dinv[s]h[s]) @ W + b ).  Hub row NOT written
// (handled by hub_kernel + hub_gemm).  No atomics, pure writes.
// LDS 42.4 KB -> 3 blocks/CU; GEMM VALU hides in gather latency of co-resident
// blocks (pull VALUBusy was 9% in R5).
// ---------------------------------------------------------------------------
__global__ __launch_bounds__(384)
void pull_fused(const float* __restrict__ h, const float* __restrict__ dinv,
                const int* __restrict__ rowptr, const int* __restrict__ col,
                int N, int HUB, const float* __restrict__ W,
                const float* __restrict__ bias, int relu,
                float* __restrict__ out) {
    __shared__ float Wl[FD * FD];      // 36864 B
    __shared__ float As[16 * 100];     // 6400 B (pad 100)
    int c = threadIdx.x;               // 0..23
    int y = threadIdx.y;               // 0..15
    int t = y * 24 + c;                // 0..383

    {   // stage W
        const float4* W4 = (const float4*)W;
        float4* Wl4 = (float4*)Wl;
        #pragma unroll
        for (int i = t; i < FD * 24; i += 384) Wl4[i] = W4[i];
    }

    int n = blockIdx.x * 16 + y;
    bool active = (n < N) && (n != HUB);
    const float4* h4 = (const float4*)h;
    float ax = 0.f, ay = 0.f, az = 0.f, aw = 0.f;
    float dn = 0.f;
    if (active) {
        dn = dinv[n];
        int beg = rowptr[n], end = rowptr[n + 1];
        int e = beg;
        for (; e + 8 <= end; e += 8) {
            int s0 = col[e + 0], s1 = col[e + 1], s2 = col[e + 2], s3 = col[e + 3];
            int s4 = col[e + 4], s5 = col[e + 5], s6 = col[e + 6], s7 = col[e + 7];
            float w0 = dinv[s0], w1 = dinv[s1], w2 = dinv[s2], w3 = dinv[s3];
            float w4 = dinv[s4], w5 = dinv[s5], w6 = dinv[s6], w7 = dinv[s7];
            float4 v0 = h4[(long)s0 * 24 + c], v1 = h4[(long)s1 * 24 + c];
            float4 v2 = h4[(long)s2 * 24 + c], v3 = h4[(long)s3 * 24 + c];
            float4 v4 = h4[(long)s4 * 24 + c], v5 = h4[(long)s5 * 24 + c];
            float4 v6 = h4[(long)s6 * 24 + c], v7 = h4[(long)s7 * 24 + c];
            ax = fmaf(w0, v0.x, fmaf(w1, v1.x, fmaf(w2, v2.x, fmaf(w3, v3.x,
                 fmaf(w4, v4.x, fmaf(w5, v5.x, fmaf(w6, v6.x, fmaf(w7, v7.x, ax))))))));
            ay = fmaf(w0, v0.y, fmaf(w1, v1.y, fmaf(w2, v2.y, fmaf(w3, v3.y,
                 fmaf(w4, v4.y, fmaf(w5, v5.y, fmaf(w6, v6.y, fmaf(w7, v7.y, ay))))))));
            az = fmaf(w0, v0.z, fmaf(w1, v1.z, fmaf(w2, v2.z, fmaf(w3, v3.z,
                 fmaf(w4, v4.z, fmaf(w5, v5.z, fmaf(w6, v6.z, fmaf(w7, v7.z, az))))))));
            aw = fmaf(w0, v0.w, fmaf(w1, v1.w, fmaf(w2, v2.w, fmaf(w3, v3.w,
                 fmaf(w4, v4.w, fmaf(w5, v5.w, fmaf(w6, v6.w, fmaf(w7, v7.w, aw))))))));
        }
        for (; e < end; e++) {
            int s = col[e];
            float w = dinv[s];
            float4 v = h4[(long)s * 24 + c];
            ax = fmaf(w, v.x, ax); ay = fmaf(w, v.y, ay);
            az = fmaf(w, v.z, az); aw = fmaf(w, v.w, aw);
        }
    }
    *(float4*)&As[y * 100 + 4 * c] = make_float4(ax * dn, ay * dn, az * dn, aw * dn);
    __syncthreads();

    // in-block GEMM: row y, cols 4c..4c+3
    float4 acc = make_float4(0.f, 0.f, 0.f, 0.f);
    for (int kk = 0; kk < FD; kk += 4) {
        float4 w0 = *(const float4*)&Wl[(kk + 0) * FD + 4 * c];
        float4 w1 = *(const float4*)&Wl[(kk + 1) * FD + 4 * c];
        float4 w2 = *(const float4*)&Wl[(kk + 2) * FD + 4 * c];
        float4 w3 = *(const float4*)&Wl[(kk + 3) * FD + 4 * c];
        float4 a = *(const float4*)&As[y * 100 + kk];
        acc.x = fmaf(a.x, w0.x, fmaf(a.y, w1.x, fmaf(a.z, w2.x, fmaf(a.w, w3.x, acc.x))));
        acc.y = fmaf(a.x, w0.y, fmaf(a.y, w1.y, fmaf(a.z, w2.y, fmaf(a.w, w3.y, acc.y))));
        acc.z = fmaf(a.x, w0.z, fmaf(a.y, w1.z, fmaf(a.z, w2.z, fmaf(a.w, w3.z, acc.z))));
        acc.w = fmaf(a.x, w0.w, fmaf(a.y, w1.w, fmaf(a.z, w2.w, fmaf(a.w, w3.w, acc.w))));
    }
    if (active) {
        float4 b4 = *(const float4*)&bias[4 * c];
        acc.x += b4.x; acc.y += b4.y; acc.z += b4.z; acc.w += b4.w;
        if (relu) {
            acc.x = fmaxf(acc.x, 0.f); acc.y = fmaxf(acc.y, 0.f);
            acc.z = fmaxf(acc.z, 0.f); acc.w = fmaxf(acc.w, 0.f);
        }
        ((float4*)out)[(long)n * 24 + c] = acc;
    }
}

// ---------------------------------------------------------------------------
// K6: plain pull aggregation (layer 2): out[n] = dinv[n]*sum dinv[s]h[s].
// Zeroes hub row (hub_kernel adds it after).
// ---------------------------------------------------------------------------
__global__ __launch_bounds__(384)
void pull_kernel(const float* __restrict__ h, const float* __restrict__ dinv,
                 const int* __restrict__ rowptr, const int* __restrict__ col,
                 int N, int HUB, float* __restrict__ out) {
    int c = threadIdx.x;
    int n = blockIdx.x * 16 + threadIdx.y;
    if (n >= N) return;
    const float4* h4 = (const float4*)h;
    float4* out4 = (float4*)out;
    long ob = (long)n * 24 + c;
    if (n == HUB) { out4[ob] = make_float4(0.f, 0.f, 0.f, 0.f); return; }
    int beg = rowptr[n], end = rowptr[n + 1];
    float dn = dinv[n];
    float ax = 0.f, ay = 0.f, az = 0.f, aw = 0.f;
    int e = beg;
    for (; e + 8 <= end; e += 8) {
        int s0 = col[e + 0], s1 = col[e + 1], s2 = col[e + 2], s3 = col[e + 3];
        int s4 = col[e + 4], s5 = col[e + 5], s6 = col[e + 6], s7 = col[e + 7];
        float w0 = dinv[s0], w1 = dinv[s1], w2 = dinv[s2], w3 = dinv[s3];
        float w4 = dinv[s4], w5 = dinv[s5], w6 = dinv[s6], w7 = dinv[s7];
        float4 v0 = h4[(long)s0 * 24 + c], v1 = h4[(long)s1 * 24 + c];
        float4 v2 = h4[(long)s2 * 24 + c], v3 = h4[(long)s3 * 24 + c];
        float4 v4 = h4[(long)s4 * 24 + c], v5 = h4[(long)s5 * 24 + c];
        float4 v6 = h4[(long)s6 * 24 + c], v7 = h4[(long)s7 * 24 + c];
        ax = fmaf(w0, v0.x, fmaf(w1, v1.x, fmaf(w2, v2.x, fmaf(w3, v3.x,
             fmaf(w4, v4.x, fmaf(w5, v5.x, fmaf(w6, v6.x, fmaf(w7, v7.x, ax))))))));
        ay = fmaf(w0, v0.y, fmaf(w1, v1.y, fmaf(w2, v2.y, fmaf(w3, v3.y,
             fmaf(w4, v4.y, fmaf(w5, v5.y, fmaf(w6, v6.y, fmaf(w7, v7.y, ay))))))));
        az = fmaf(w0, v0.z, fmaf(w1, v1.z, fmaf(w2, v2.z, fmaf(w3, v3.z,
             fmaf(w4, v4.z, fmaf(w5, v5.z, fmaf(w6, v6.z, fmaf(w7, v7.z, az))))))));
        aw = fmaf(w0, v0.w, fmaf(w1, v1.w, fmaf(w2, v2.w, fmaf(w3, v3.w,
             fmaf(w4, v4.w, fmaf(w5, v5.w, fmaf(w6, v6.w, fmaf(w7, v7.w, aw))))))));
    }
    for (; e < end; e++) {
        int s = col[e];
        float w = dinv[s];
        float4 v = h4[(long)s * 24 + c];
        ax = fmaf(w, v.x, ax); ay = fmaf(w, v.y, ay);
        az = fmaf(w, v.z, az); aw = fmaf(w, v.w, aw);
    }
    out4[ob] = make_float4(ax * dn, ay * dn, az * dn, aw * dn);
}

// ---------------------------------------------------------------------------
// K7: hub row aggregation into dest[96] (pre-zeroed): dest += dinv[HUB] *
// sum dinv[s]h[s].  256 blocks x 8 streams, 4-deep unroll, LDS reduce,
// 96 atomics/block.
// ---------------------------------------------------------------------------
__global__ __launch_bounds__(192)
void hub_kernel(const float* __restrict__ h, const float* __restrict__ dinv,
                const int* __restrict__ rowptr, const int* __restrict__ col,
                int HUB, float* __restrict__ dest) {
    int c = threadIdx.x;   // 0..23
    int y = threadIdx.y;   // 0..7
    const float4* h4 = (const float4*)h;
    int beg = rowptr[HUB], end = rowptr[HUB + 1];
    int deg = end - beg;
    int nstr = gridDim.x * 8;
    int sid  = blockIdx.x * 8 + y;
    int chunk = (deg + nstr - 1) / nstr;
    int e  = beg + sid * chunk;
    int e1 = min(e + chunk, end);
    float ax = 0.f, ay = 0.f, az = 0.f, aw = 0.f;
    for (; e + 4 <= e1; e += 4) {
        int s0 = col[e + 0], s1 = col[e + 1], s2 = col[e + 2], s3 = col[e + 3];
        float w0 = dinv[s0], w1 = dinv[s1], w2 = dinv[s2], w3 = dinv[s3];
        float4 v0 = h4[(long)s0 * 24 + c], v1 = h4[(long)s1 * 24 + c];
        float4 v2 = h4[(long)s2 * 24 + c], v3 = h4[(long)s3 * 24 + c];
        ax = fmaf(w0, v0.x, fmaf(w1, v1.x, fmaf(w2, v2.x, fmaf(w3, v3.x, ax))));
        ay = fmaf(w0, v0.y, fmaf(w1, v1.y, fmaf(w2, v2.y, fmaf(w3, v3.y, ay))));
        az = fmaf(w0, v0.z, fmaf(w1, v1.z, fmaf(w2, v2.z, fmaf(w3, v3.z, az))));
        aw = fmaf(w0, v0.w, fmaf(w1, v1.w, fmaf(w2, v2.w, fmaf(w3, v3.w, aw))));
    }
    for (; e < e1; e++) {
        int s = col[e];
        float w = dinv[s];
        float4 v = h4[(long)s * 24 + c];
        ax = fmaf(w, v.x, ax); ay = fmaf(w, v.y, ay);
        az = fmaf(w, v.z, az); aw = fmaf(w, v.w, aw);
    }
    __shared__ float4 red[8][24];
    red[y][c] = make_float4(ax, ay, az, aw);
    __syncthreads();
    if (y == 0) {
        float4 t = red[0][c];
        #pragma unroll
        for (int k = 1; k < 8; k++) {
            float4 u = red[k][c];
            t.x += u.x; t.y += u.y; t.z += u.z; t.w += u.w;
        }
        float dh = dinv[HUB];
        float* o = dest + 4 * c;
        unsafeAtomicAdd(o + 0, t.x * dh);
        unsafeAtomicAdd(o + 1, t.y * dh);
        unsafeAtomicAdd(o + 2, t.z * dh);
        unsafeAtomicAdd(o + 3, t.w * dh);
    }
}

// ---------------------------------------------------------------------------
// K8: single-row GEMM for the hub: outrow = act(hubrow @ W + b). 1 block.
// ---------------------------------------------------------------------------
__global__ __launch_bounds__(96)
void hub_gemm(const float* __restrict__ hubrow, const float* __restrict__ W,
              const float* __restrict__ bias, int relu,
              float* __restrict__ outrow) {
    int f = threadIdx.x;   // 0..95
    float acc = bias[f];
    #pragma unroll 8
    for (int k = 0; k < FD; k++)
        acc = fmaf(hubrow[k], W[k * FD + f], acc);
    if (relu) acc = fmaxf(acc, 0.f);
    outrow[f] = acc;
}

// ---------------------------------------------------------------------------
// K9: out[N,96] = A[N,96] @ W[96,96] + bias. SAFE IN-PLACE (tile-local).
// ---------------------------------------------------------------------------
__global__ __launch_bounds__(192)
void gemm96(const float* __restrict__ A, const float* __restrict__ W,
            const float* __restrict__ bias, float* __restrict__ out,
            int N, int relu) {
    __shared__ float Wl[FD * FD];
    __shared__ float As[64 * 100];
    int t = threadIdx.y * 24 + threadIdx.x;

    {
        const float4* W4 = (const float4*)W;
        float4* Wl4 = (float4*)Wl;
        #pragma unroll 4
        for (int i = t; i < FD * 24; i += 192) Wl4[i] = W4[i];
    }
    int row0 = blockIdx.x * 64;
    int nrows = min(64, N - row0);
    {
        const float4* A4 = (const float4*)(A + (long)row0 * FD);
        for (int i = t; i < nrows * 24; i += 192) {
            int r = i / 24, g = i % 24;
            *(float4*)&As[r * 100 + g * 4] = A4[i];
        }
    }
    __syncthreads();

    int c = threadIdx.x;
    int y = threadIdx.y;
    float acc[8][4];
    #pragma unroll
    for (int j = 0; j < 8; j++)
        #pragma unroll
        for (int i = 0; i < 4; i++) acc[j][i] = 0.f;

    for (int kk = 0; kk < FD; kk += 4) {
        float4 w0 = *(const float4*)&Wl[(kk + 0) * FD + 4 * c];
        float4 w1 = *(const float4*)&Wl[(kk + 1) * FD + 4 * c];
        float4 w2 = *(const float4*)&Wl[(kk + 2) * FD + 4 * c];
        float4 w3 = *(const float4*)&Wl[(kk + 3) * FD + 4 * c];
        #pragma unroll
        for (int j = 0; j < 8; j++) {
            float4 a = *(const float4*)&As[(y + 8 * j) * 100 + kk];
            acc[j][0] = fmaf(a.x, w0.x, fmaf(a.y, w1.x, fmaf(a.z, w2.x, fmaf(a.w, w3.x, acc[j][0]))));
            acc[j][1] = fmaf(a.x, w0.y, fmaf(a.y, w1.y, fmaf(a.z, w2.y, fmaf(a.w, w3.y, acc[j][1]))));
            acc[j][2] = fmaf(a.x, w0.z, fmaf(a.y, w1.z, fmaf(a.z, w2.z, fmaf(a.w, w3.z, acc[j][2]))));
            acc[j][3] = fmaf(a.x, w0.w, fmaf(a.y, w1.w, fmaf(a.z, w2.w, fmaf(a.w, w3.w, acc[j][3]))));
        }
    }

    float4 b4 = *(const float4*)&bias[4 * c];
    #pragma unroll
    for (int j = 0; j < 8; j++) {
        int r = y + 8 * j;
        if (r < nrows) {
            float4 v;
            v.x = acc[j][0] + b4.x; v.y = acc[j][1] + b4.y;
            v.z = acc[j][2] + b4.z; v.w = acc[j][3] + b4.w;
            if (relu) {
                v.x = fmaxf(v.x, 0.f); v.y = fmaxf(v.y, 0.f);
                v.z = fmaxf(v.z, 0.f); v.w = fmaxf(v.w, 0.f);
            }
            *(float4*)&out[(long)(row0 + r) * FD + 4 * c] = v;
        }
    }
}

// ---------------------------------------------------------------------------
// Launch.  (A@X)@W == A@(X@W); layer-1 GEMM fused into the pull.
//   h1 = relu((A@x)@W1+b1)  -> ls slot  (pull_fused; hub row via hub path)
//   a1 = A@h1               -> mu slot  (pull + hub)
//   ls = a1@W2b+b2b         -> ls slot  (h1 dead)       [W2b FIRST]
//   mu = a1@W2a+b2a         -> mu slot  (in-place, tile-local)
// ws: [counts N][cursor N][hubacc 96][rowptr N+1][col E][dinv N]  (~4.4 MB)
// ---------------------------------------------------------------------------
extern "C" void kernel_launch(void* const* d_in, const int* in_sizes, int n_in,
                              void* d_out, int out_size, void* d_ws, size_t ws_size,
                              hipStream_t stream) {
    const float* x   = (const float*)d_in[0];
    const float* W1  = (const float*)d_in[1];
    const float* b1  = (const float*)d_in[2];
    const float* W2a = (const float*)d_in[3];
    const float* b2a = (const float*)d_in[4];
    const float* W2b = (const float*)d_in[5];
    const float* b2b = (const float*)d_in[6];
    const int*   ei  = (const int*)d_in[7];

    const int N   = in_sizes[0] / FD;
    const int E   = in_sizes[7] / 2;
    const int HUB = N - 1;
    const int* src = ei;
    const int* dst = ei + E;

    int* counts   = (int*)d_ws;
    int* cursor   = counts + N;
    float* hubacc = (float*)(cursor + N);      // 96 floats
    int* rowptr   = (int*)(hubacc + FD);
    int* col      = rowptr + (N + 1);
    float* dinv   = (float*)(col + E);

    float* mu = (float*)d_out;
    float* ls = (float*)d_out + (size_t)N * FD;
    float* h1 = ls;
    float* a1 = mu;

    // zero counts + cursor + hubacc (contiguous)
    hipMemsetAsync(counts, 0, ((size_t)2 * N + FD) * sizeof(int), stream);

    // CSR build (reused by both layers)
    deg_kernel <<<dim3((E + 255) / 256), dim3(256), 0, stream>>>(dst, E, HUB, counts);
    scan_kernel<<<dim3(1), dim3(1024), 0, stream>>>(counts, rowptr, N);
    fill_kernel<<<dim3((E + 255) / 256), dim3(256), 0, stream>>>(src, dst, E, HUB,
                                                                 rowptr, cursor, col);
    dinv_kernel<<<dim3((N + 255) / 256), dim3(256), 0, stream>>>(counts, dinv, N);

    dim3 pullB(24, 16);
    int  pullG = (N + 15) / 16;
    dim3 hubB(24, 8);
    int  hubG = 256;
    int  gemmG = (N + 63) / 64;
    dim3 gemmB(24, 8);

    // layer 1: h1 = relu((A@x)@W1+b1), GEMM fused into pull
    pull_fused<<<dim3(pullG), pullB, 0, stream>>>(x, dinv, rowptr, col, N, HUB,
                                                  W1, b1, 1, h1);
    hub_kernel<<<dim3(hubG), hubB, 0, stream>>>(x, dinv, rowptr, col, HUB, hubacc);
    hub_gemm  <<<dim3(1), dim3(96), 0, stream>>>(hubacc, W1, b1, 1,
                                                 h1 + (size_t)HUB * FD);

    // layer 2: a1 = A@h1 (shared by mu and logstd)
    pull_kernel<<<dim3(pullG), pullB, 0, stream>>>(h1, dinv, rowptr, col, N, HUB, a1);
    hub_kernel <<<dim3(hubG),  hubB, 0, stream>>>(h1, dinv, rowptr, col, HUB,
                                                  a1 + (size_t)HUB * FD);
    gemm96<<<dim3(gemmG), gemmB, 0, stream>>>(a1, W2b, b2b, ls, N, 0);  // ls first
    gemm96<<<dim3(gemmG), gemmB, 0, stream>>>(a1, W2a, b2a, mu, N, 0);  // in-place
}

// Round 7
// 390.520 us; speedup vs baseline: 1.2014x; 1.2014x over previous
//
#include <hip/hip_runtime.h>

#define FD 96   // feature dim

// ---------------------------------------------------------------------------
// K1: degree histogram + per-edge rank capture. perm[e] = this edge's order
// among edges with the same dst (rank from the counting atomic). Hub handled
// via ballot+popcount: one atomic per wave instead of ~50k serialized.
// ---------------------------------------------------------------------------
__global__ void deg_kernel(const int* __restrict__ dst, int E, int HUB,
                           int* __restrict__ counts, int* __restrict__ perm) {
    int e = blockIdx.x * 256 + threadIdx.x;
    int d = (e < E) ? dst[e] : -1;
    bool isHub = (d == HUB);
    unsigned long long m = __ballot(isHub);
    if (isHub) {
        int lane = threadIdx.x & 63;
        int leader = __ffsll((unsigned long long)m) - 1;
        int base = 0;
        if (lane == leader) base = atomicAdd(&counts[HUB], (int)__popcll(m));
        base = __shfl(base, leader);
        unsigned long long below = m & ((1ull << lane) - 1ull);
        perm[e] = base + (int)__popcll(below);
    } else if (d >= 0) {
        perm[e] = atomicAdd(&counts[d], 1);
    }
}

// ---------------------------------------------------------------------------
// K2a: per-1024-chunk partial sums of counts -> bsum[block]
// ---------------------------------------------------------------------------
__global__ __launch_bounds__(1024)
void scan_partial(const int* __restrict__ counts, int N, int* __restrict__ bsum) {
    int i = blockIdx.x * 1024 + threadIdx.x;
    int v = (i < N) ? counts[i] : 0;
    #pragma unroll
    for (int off = 32; off; off >>= 1) v += __shfl_down(v, off);
    __shared__ int ws_[16];
    int t = threadIdx.x;
    if ((t & 63) == 0) ws_[t >> 6] = v;
    __syncthreads();
    if (t == 0) {
        int s = 0;
        #pragma unroll
        for (int k = 0; k < 16; k++) s += ws_[k];
        bsum[blockIdx.x] = s;
    }
}

// ---------------------------------------------------------------------------
// K2b: single-block exclusive scan of bsum[NB] (NB<=1024), in-place; writes
// grand total to rowptr[N].
// ---------------------------------------------------------------------------
__global__ __launch_bounds__(1024)
void scan_bsum(int* __restrict__ bsum, int NB, int* __restrict__ rowptr, int N) {
    int t = threadIdx.x, lane = t & 63, wv = t >> 6;
    int v = (t < NB) ? bsum[t] : 0;
    int x = v;
    #pragma unroll
    for (int off = 1; off < 64; off <<= 1) {
        int u = __shfl_up(x, off);
        if (lane >= off) x += u;
    }
    __shared__ int wsum[16];
    if (lane == 63) wsum[wv] = x;
    __syncthreads();
    if (wv == 0 && lane < 16) {
        int w = wsum[lane];
        #pragma unroll
        for (int off = 1; off < 16; off <<= 1) {
            int u = __shfl_up(w, off);
            if (lane >= off) w += u;
        }
        wsum[lane] = w;
    }
    __syncthreads();
    int waveoff = (wv == 0) ? 0 : wsum[wv - 1];
    int incl = waveoff + x;
    if (t < NB) bsum[t] = incl - v;          // exclusive chunk offset
    if (t == 1023) rowptr[N] = incl;         // grand total (padding lanes add 0)
}

// ---------------------------------------------------------------------------
// K2c: apply — rowptr[i] = bsum[chunk] + exclusive_scan_within_chunk(counts)
// ---------------------------------------------------------------------------
__global__ __launch_bounds__(1024)
void scan_apply(const int* __restrict__ counts, const int* __restrict__ bsum,
                int N, int* __restrict__ rowptr) {
    int i = blockIdx.x * 1024 + threadIdx.x;
    int t = threadIdx.x, lane = t & 63, wv = t >> 6;
    int v = (i < N) ? counts[i] : 0;
    int x = v;
    #pragma unroll
    for (int off = 1; off < 64; off <<= 1) {
        int u = __shfl_up(x, off);
        if (lane >= off) x += u;
    }
    __shared__ int wsum[16];
    if (lane == 63) wsum[wv] = x;
    __syncthreads();
    if (wv == 0 && lane < 16) {
        int w = wsum[lane];
        #pragma unroll
        for (int off = 1; off < 16; off <<= 1) {
            int u = __shfl_up(w, off);
            if (lane >= off) w += u;
        }
        wsum[lane] = w;
    }
    __syncthreads();
    int waveoff = (wv == 0) ? 0 : wsum[wv - 1];
    if (i < N) rowptr[i] = bsum[blockIdx.x] + waveoff + x - v;   // exclusive
}

// ---------------------------------------------------------------------------
// K3: fill CSR col[] — ATOMIC-FREE (rank precomputed in perm[]).
// ---------------------------------------------------------------------------
__global__ void fill_kernel(const int* __restrict__ src, const int* __restrict__ dst,
                            const int* __restrict__ perm,
                            const int* __restrict__ rowptr, int E,
                            int* __restrict__ col) {
    int e = blockIdx.x * 256 + threadIdx.x;
    if (e >= E) return;
    int d = dst[e];
    col[rowptr[d] + perm[e]] = src[e];
}

// ---------------------------------------------------------------------------
// K4: dinv from int counts
// ---------------------------------------------------------------------------
__global__ void dinv_kernel(const int* __restrict__ counts, float* __restrict__ dinv,
                            int N) {
    int n = blockIdx.x * 256 + threadIdx.x;
    if (n < N) {
        float d = (float)counts[n];
        dinv[n] = (d > 0.f) ? rsqrtf(fmaxf(d, 1.f)) : 0.f;
    }
}

// ---------------------------------------------------------------------------
// K5: pull aggregation (light rows): out[n] = dinv[n]*sum dinv[s]h[s].
// block (24,16), float4 lanes, 8-deep unrolled edge loop for MLP. Pure
// writes. Hub row zeroed here (hub_kernel adds it after).
// ---------------------------------------------------------------------------
__global__ __launch_bounds__(384)
void pull_kernel(const float* __restrict__ h, const float* __restrict__ dinv,
                 const int* __restrict__ rowptr, const int* __restrict__ col,
                 int N, int HUB, float* __restrict__ out) {
    int c = threadIdx.x;
    int n = blockIdx.x * 16 + threadIdx.y;
    if (n >= N) return;
    const float4* h4 = (const float4*)h;
    float4* out4 = (float4*)out;
    long ob = (long)n * 24 + c;
    if (n == HUB) { out4[ob] = make_float4(0.f, 0.f, 0.f, 0.f); return; }
    int beg = rowptr[n], end = rowptr[n + 1];
    float dn = dinv[n];
    float ax = 0.f, ay = 0.f, az = 0.f, aw = 0.f;
    int e = beg;
    for (; e + 8 <= end; e += 8) {
        int s0 = col[e + 0], s1 = col[e + 1], s2 = col[e + 2], s3 = col[e + 3];
        int s4 = col[e + 4], s5 = col[e + 5], s6 = col[e + 6], s7 = col[e + 7];
        float w0 = dinv[s0], w1 = dinv[s1], w2 = dinv[s2], w3 = dinv[s3];
        float w4 = dinv[s4], w5 = dinv[s5], w6 = dinv[s6], w7 = dinv[s7];
        float4 v0 = h4[(long)s0 * 24 + c], v1 = h4[(long)s1 * 24 + c];
        float4 v2 = h4[(long)s2 * 24 + c], v3 = h4[(long)s3 * 24 + c];
        float4 v4 = h4[(long)s4 * 24 + c], v5 = h4[(long)s5 * 24 + c];
        float4 v6 = h4[(long)s6 * 24 + c], v7 = h4[(long)s7 * 24 + c];
        ax = fmaf(w0, v0.x, fmaf(w1, v1.x, fmaf(w2, v2.x, fmaf(w3, v3.x,
             fmaf(w4, v4.x, fmaf(w5, v5.x, fmaf(w6, v6.x, fmaf(w7, v7.x, ax))))))));
        ay = fmaf(w0, v0.y, fmaf(w1, v1.y, fmaf(w2, v2.y, fmaf(w3, v3.y,
             fmaf(w4, v4.y, fmaf(w5, v5.y, fmaf(w6, v6.y, fmaf(w7, v7.y, ay))))))));
        az = fmaf(w0, v0.z, fmaf(w1, v1.z, fmaf(w2, v2.z, fmaf(w3, v3.z,
             fmaf(w4, v4.z, fmaf(w5, v5.z, fmaf(w6, v6.z, fmaf(w7, v7.z, az))))))));
        aw = fmaf(w0, v0.w, fmaf(w1, v1.w, fmaf(w2, v2.w, fmaf(w3, v3.w,
             fmaf(w4, v4.w, fmaf(w5, v5.w, fmaf(w6, v6.w, fmaf(w7, v7.w, aw))))))));
    }
    for (; e < end; e++) {
        int s = col[e];
        float w = dinv[s];
        float4 v = h4[(long)s * 24 + c];
        ax = fmaf(w, v.x, ax); ay = fmaf(w, v.y, ay);
        az = fmaf(w, v.z, az); aw = fmaf(w, v.w, aw);
    }
    out4[ob] = make_float4(ax * dn, ay * dn, az * dn, aw * dn);
}

// ---------------------------------------------------------------------------
// K6: hub row aggregation: dest[0..95] += dinv[HUB]*sum dinv[s]h[s] over the
// hub's edges (dest pre-zeroed by pull_kernel). 256 blocks x 8 streams,
// 4-deep unroll, LDS reduce, 96 atomics/block.
// ---------------------------------------------------------------------------
__global__ __launch_bounds__(192)
void hub_kernel(const float* __restrict__ h, const float* __restrict__ dinv,
                const int* __restrict__ rowptr, const int* __restrict__ col,
                int HUB, float* __restrict__ dest) {
    int c = threadIdx.x;   // 0..23
    int y = threadIdx.y;   // 0..7
    const float4* h4 = (const float4*)h;
    int beg = rowptr[HUB], end = rowptr[HUB + 1];
    int deg = end - beg;
    int nstr = gridDim.x * 8;
    int sid  = blockIdx.x * 8 + y;
    int chunk = (deg + nstr - 1) / nstr;
    int e  = beg + sid * chunk;
    int e1 = min(e + chunk, end);
    float ax = 0.f, ay = 0.f, az = 0.f, aw = 0.f;
    for (; e + 4 <= e1; e += 4) {
        int s0 = col[e + 0], s1 = col[e + 1], s2 = col[e + 2], s3 = col[e + 3];
        float w0 = dinv[s0], w1 = dinv[s1], w2 = dinv[s2], w3 = dinv[s3];
        float4 v0 = h4[(long)s0 * 24 + c], v1 = h4[(long)s1 * 24 + c];
        float4 v2 = h4[(long)s2 * 24 + c], v3 = h4[(long)s3 * 24 + c];
        ax = fmaf(w0, v0.x, fmaf(w1, v1.x, fmaf(w2, v2.x, fmaf(w3, v3.x, ax))));
        ay = fmaf(w0, v0.y, fmaf(w1, v1.y, fmaf(w2, v2.y, fmaf(w3, v3.y, ay))));
        az = fmaf(w0, v0.z, fmaf(w1, v1.z, fmaf(w2, v2.z, fmaf(w3, v3.z, az))));
        aw = fmaf(w0, v0.w, fmaf(w1, v1.w, fmaf(w2, v2.w, fmaf(w3, v3.w, aw))));
    }
    for (; e < e1; e++) {
        int s = col[e];
        float w = dinv[s];
        float4 v = h4[(long)s * 24 + c];
        ax = fmaf(w, v.x, ax); ay = fmaf(w, v.y, ay);
        az = fmaf(w, v.z, az); aw = fmaf(w, v.w, aw);
    }
    __shared__ float4 red[8][24];
    red[y][c] = make_float4(ax, ay, az, aw);
    __syncthreads();
    if (y == 0) {
        float4 t = red[0][c];
        #pragma unroll
        for (int k = 1; k < 8; k++) {
            float4 u = red[k][c];
            t.x += u.x; t.y += u.y; t.z += u.z; t.w += u.w;
        }
        float dh = dinv[HUB];
        float* o = dest + 4 * c;
        unsafeAtomicAdd(o + 0, t.x * dh);
        unsafeAtomicAdd(o + 1, t.y * dh);
        unsafeAtomicAdd(o + 2, t.z * dh);
        unsafeAtomicAdd(o + 3, t.w * dh);
    }
}

// ---------------------------------------------------------------------------
// K7: out[N,96] = A[N,96] @ W[96,96] + bias (optional relu).
// SAFE IN-PLACE (out may == A): full 64-row tile staged into LDS behind
// __syncthreads before any write; blocks only write their own tile rows.
// ---------------------------------------------------------------------------
__global__ __launch_bounds__(192)
void gemm96(const float* __restrict__ A, const float* __restrict__ W,
            const float* __restrict__ bias, float* __restrict__ out,
            int N, int relu) {
    __shared__ float Wl[FD * FD];        // 36864 B
    __shared__ float As[64 * 100];       // 25600 B
    int t = threadIdx.y * 24 + threadIdx.x;

    {
        const float4* W4 = (const float4*)W;
        float4* Wl4 = (float4*)Wl;
        #pragma unroll 4
        for (int i = t; i < FD * 24; i += 192) Wl4[i] = W4[i];
    }
    int row0 = blockIdx.x * 64;
    int nrows = min(64, N - row0);
    {
        const float4* A4 = (const float4*)(A + (long)row0 * FD);
        for (int i = t; i < nrows * 24; i += 192) {
            int r = i / 24, g = i % 24;
            *(float4*)&As[r * 100 + g * 4] = A4[i];
        }
    }
    __syncthreads();

    int c = threadIdx.x;
    int y = threadIdx.y;
    float acc[8][4];
    #pragma unroll
    for (int j = 0; j < 8; j++)
        #pragma unroll
        for (int i = 0; i < 4; i++) acc[j][i] = 0.f;

    for (int kk = 0; kk < FD; kk += 4) {
        float4 w0 = *(const float4*)&Wl[(kk + 0) * FD + 4 * c];
        float4 w1 = *(const float4*)&Wl[(kk + 1) * FD + 4 * c];
        float4 w2 = *(const float4*)&Wl[(kk + 2) * FD + 4 * c];
        float4 w3 = *(const float4*)&Wl[(kk + 3) * FD + 4 * c];
        #pragma unroll
        for (int j = 0; j < 8; j++) {
            float4 a = *(const float4*)&As[(y + 8 * j) * 100 + kk];
            acc[j][0] = fmaf(a.x, w0.x, fmaf(a.y, w1.x, fmaf(a.z, w2.x, fmaf(a.w, w3.x, acc[j][0]))));
            acc[j][1] = fmaf(a.x, w0.y, fmaf(a.y, w1.y, fmaf(a.z, w2.y, fmaf(a.w, w3.y, acc[j][1]))));
            acc[j][2] = fmaf(a.x, w0.z, fmaf(a.y, w1.z, fmaf(a.z, w2.z, fmaf(a.w, w3.z, acc[j][2]))));
            acc[j][3] = fmaf(a.x, w0.w, fmaf(a.y, w1.w, fmaf(a.z, w2.w, fmaf(a.w, w3.w, acc[j][3]))));
        }
    }

    float4 b4 = *(const float4*)&bias[4 * c];
    #pragma unroll
    for (int j = 0; j < 8; j++) {
        int r = y + 8 * j;
        if (r < nrows) {
            float4 v;
            v.x = acc[j][0] + b4.x; v.y = acc[j][1] + b4.y;
            v.z = acc[j][2] + b4.z; v.w = acc[j][3] + b4.w;
            if (relu) {
                v.x = fmaxf(v.x, 0.f); v.y = fmaxf(v.y, 0.f);
                v.z = fmaxf(v.z, 0.f); v.w = fmaxf(v.w, 0.f);
            }
            *(float4*)&out[(long)(row0 + r) * FD + 4 * c] = v;
        }
    }
}

// ---------------------------------------------------------------------------
// Launch.  (A@X)@W == A@(X@W) reassociation shares the aggregation.
// All N*96 temporaries inside d_out via liveness aliasing (ws ~11.4 MB):
//   a0 = A@x            -> ls slot   (pull + hub)
//   h1 = relu(a0@W1+b1) -> mu slot
//   a1 = A@h1           -> ls slot   (a0 dead; pull + hub)
//   mu = a1@W2a+b2a     -> mu slot   (h1 dead)
//   ls = a1@W2b+b2b     -> ls slot   (in-place; gemm96 is tile-local)
// ---------------------------------------------------------------------------
extern "C" void kernel_launch(void* const* d_in, const int* in_sizes, int n_in,
                              void* d_out, int out_size, void* d_ws, size_t ws_size,
                              hipStream_t stream) {
    const float* x   = (const float*)d_in[0];
    const float* W1  = (const float*)d_in[1];
    const float* b1  = (const float*)d_in[2];
    const float* W2a = (const float*)d_in[3];
    const float* b2a = (const float*)d_in[4];
    const float* W2b = (const float*)d_in[5];
    const float* b2b = (const float*)d_in[6];
    const int*   ei  = (const int*)d_in[7];

    const int N   = in_sizes[0] / FD;
    const int E   = in_sizes[7] / 2;
    const int HUB = N - 1;
    const int* src = ei;
    const int* dst = ei + E;
    const int NB  = (N + 1023) / 1024;   // scan chunks (<=1024)

    // ws: [counts N][perm E][bsum 1024][rowptr N+1][col E][dinv N]  (~11.4 MB)
    int* counts = (int*)d_ws;
    int* perm   = counts + N;
    int* bsum   = perm + E;
    int* rowptr = bsum + 1024;
    int* col    = rowptr + (N + 1);
    float* dinv = (float*)(col + E);

    float* mu = (float*)d_out;
    float* ls = (float*)d_out + (size_t)N * FD;
    float* a0 = ls;
    float* h1 = mu;
    float* a1 = ls;

    hipMemsetAsync(counts, 0, (size_t)N * sizeof(int), stream);

    // CSR build (reused by both layers)
    deg_kernel  <<<dim3((E + 255) / 256), dim3(256), 0, stream>>>(dst, E, HUB,
                                                                  counts, perm);
    scan_partial<<<dim3(NB), dim3(1024), 0, stream>>>(counts, N, bsum);
    scan_bsum   <<<dim3(1),  dim3(1024), 0, stream>>>(bsum, NB, rowptr, N);
    scan_apply  <<<dim3(NB), dim3(1024), 0, stream>>>(counts, bsum, N, rowptr);
    fill_kernel <<<dim3((E + 255) / 256), dim3(256), 0, stream>>>(src, dst, perm,
                                                                  rowptr, E, col);
    dinv_kernel <<<dim3((N + 255) / 256), dim3(256), 0, stream>>>(counts, dinv, N);

    dim3 pullB(24, 16);
    int  pullG = (N + 15) / 16;
    dim3 hubB(24, 8);
    int  hubG = 256;
    int  gemmG = (N + 63) / 64;
    dim3 gemmB(24, 8);

    // layer 1
    pull_kernel<<<dim3(pullG), pullB, 0, stream>>>(x, dinv, rowptr, col, N, HUB, a0);
    hub_kernel <<<dim3(hubG),  hubB, 0, stream>>>(x, dinv, rowptr, col, HUB,
                                                  a0 + (size_t)HUB * FD);
    gemm96     <<<dim3(gemmG), gemmB, 0, stream>>>(a0, W1, b1, h1, N, 1);

    // layer 2 (aggregation shared by mu and logstd)
    pull_kernel<<<dim3(pullG), pullB, 0, stream>>>(h1, dinv, rowptr, col, N, HUB, a1);
    hub_kernel <<<dim3(hubG),  hubB, 0, stream>>>(h1, dinv, rowptr, col, HUB,
                                                  a1 + (size_t)HUB * FD);
    gemm96<<<dim3(gemmG), gemmB, 0, stream>>>(a1, W2a, b2a, mu, N, 0);
    gemm96<<<dim3(gemmG), gemmB, 0, stream>>>(a1, W2b, b2b, ls, N, 0);  // in-place
}

// Round 8
// 349.081 us; speedup vs baseline: 1.3441x; 1.1187x over previous
//
#include <hip/hip_runtime.h>
#include <hip/hip_fp16.h>

#define FD 96   // feature dim

// ---- fp16 pack/unpack helpers (4 halves in an int2) -----------------------
__device__ inline float2 unpack2(int v) {
    __half2 h = *reinterpret_cast<__half2*>(&v);
    return __half22float2(h);
}
__device__ inline int2 pack4(float a, float b, float c, float d) {
    __half2 lo = __floats2half2_rn(a, b);
    __half2 hi = __floats2half2_rn(c, d);
    int2 r;
    r.x = *reinterpret_cast<int*>(&lo);
    r.y = *reinterpret_cast<int*>(&hi);
    return r;
}

// ---------------------------------------------------------------------------
// K1: degree histogram + per-edge rank capture (perm). Hub via ballot.
// ---------------------------------------------------------------------------
__global__ void deg_kernel(const int* __restrict__ dst, int E, int HUB,
                           int* __restrict__ counts, int* __restrict__ perm) {
    int e = blockIdx.x * 256 + threadIdx.x;
    int d = (e < E) ? dst[e] : -1;
    bool isHub = (d == HUB);
    unsigned long long m = __ballot(isHub);
    if (isHub) {
        int lane = threadIdx.x & 63;
        int leader = __ffsll((unsigned long long)m) - 1;
        int base = 0;
        if (lane == leader) base = atomicAdd(&counts[HUB], (int)__popcll(m));
        base = __shfl(base, leader);
        unsigned long long below = m & ((1ull << lane) - 1ull);
        perm[e] = base + (int)__popcll(below);
    } else if (d >= 0) {
        perm[e] = atomicAdd(&counts[d], 1);
    }
}

// ---------------------------------------------------------------------------
// K2a: per-1024-chunk partial sums of counts -> bsum[block]
// ---------------------------------------------------------------------------
__global__ __launch_bounds__(1024)
void scan_partial(const int* __restrict__ counts, int N, int* __restrict__ bsum) {
    int i = blockIdx.x * 1024 + threadIdx.x;
    int v = (i < N) ? counts[i] : 0;
    #pragma unroll
    for (int off = 32; off; off >>= 1) v += __shfl_down(v, off);
    __shared__ int ws_[16];
    int t = threadIdx.x;
    if ((t & 63) == 0) ws_[t >> 6] = v;
    __syncthreads();
    if (t == 0) {
        int s = 0;
        #pragma unroll
        for (int k = 0; k < 16; k++) s += ws_[k];
        bsum[blockIdx.x] = s;
    }
}

// ---------------------------------------------------------------------------
// K2b: single-block exclusive scan of bsum[NB]; grand total -> rowptr[N].
// ---------------------------------------------------------------------------
__global__ __launch_bounds__(1024)
void scan_bsum(int* __restrict__ bsum, int NB, int* __restrict__ rowptr, int N) {
    int t = threadIdx.x, lane = t & 63, wv = t >> 6;
    int v = (t < NB) ? bsum[t] : 0;
    int x = v;
    #pragma unroll
    for (int off = 1; off < 64; off <<= 1) {
        int u = __shfl_up(x, off);
        if (lane >= off) x += u;
    }
    __shared__ int wsum[16];
    if (lane == 63) wsum[wv] = x;
    __syncthreads();
    if (wv == 0 && lane < 16) {
        int w = wsum[lane];
        #pragma unroll
        for (int off = 1; off < 16; off <<= 1) {
            int u = __shfl_up(w, off);
            if (lane >= off) w += u;
        }
        wsum[lane] = w;
    }
    __syncthreads();
    int waveoff = (wv == 0) ? 0 : wsum[wv - 1];
    int incl = waveoff + x;
    if (t < NB) bsum[t] = incl - v;
    if (t == 1023) rowptr[N] = incl;
}

// ---------------------------------------------------------------------------
// K2c: apply scan -> rowptr[i]; ALSO emits dinv[i] (fused).
// ---------------------------------------------------------------------------
__global__ __launch_bounds__(1024)
void scan_apply(const int* __restrict__ counts, const int* __restrict__ bsum,
                int N, int* __restrict__ rowptr, float* __restrict__ dinv) {
    int i = blockIdx.x * 1024 + threadIdx.x;
    int t = threadIdx.x, lane = t & 63, wv = t >> 6;
    int v = (i < N) ? counts[i] : 0;
    int x = v;
    #pragma unroll
    for (int off = 1; off < 64; off <<= 1) {
        int u = __shfl_up(x, off);
        if (lane >= off) x += u;
    }
    __shared__ int wsum[16];
    if (lane == 63) wsum[wv] = x;
    __syncthreads();
    if (wv == 0 && lane < 16) {
        int w = wsum[lane];
        #pragma unroll
        for (int off = 1; off < 16; off <<= 1) {
            int u = __shfl_up(w, off);
            if (lane >= off) w += u;
        }
        wsum[lane] = w;
    }
    __syncthreads();
    int waveoff = (wv == 0) ? 0 : wsum[wv - 1];
    if (i < N) {
        rowptr[i] = bsum[blockIdx.x] + waveoff + x - v;
        float d = (float)v;
        dinv[i] = (d > 0.f) ? rsqrtf(fmaxf(d, 1.f)) : 0.f;
    }
}

// ---------------------------------------------------------------------------
// K3: fill CSR col[] — atomic-free (rank precomputed in perm[]).
// ---------------------------------------------------------------------------
__global__ void fill_kernel(const int* __restrict__ src, const int* __restrict__ dst,
                            const int* __restrict__ perm,
                            const int* __restrict__ rowptr, int E,
                            int* __restrict__ col) {
    int e = blockIdx.x * 256 + threadIdx.x;
    if (e >= E) return;
    int d = dst[e];
    col[rowptr[d] + perm[e]] = src[e];
}

// ---------------------------------------------------------------------------
// K4: convert — xh[n] = fp16(dinv[n] * x[n])  (prescaled fp16 features).
// Thread handles 4 features (one float4 in, one int2 out).
// ---------------------------------------------------------------------------
__global__ void convert_kernel(const float* __restrict__ x,
                               const float* __restrict__ dinv, int N,
                               int2* __restrict__ xh) {
    int i = blockIdx.x * 256 + threadIdx.x;
    if (i >= N * 24) return;
    int n = i / 24;
    float dn = dinv[n];
    float4 a = ((const float4*)x)[i];
    xh[i] = pack4(a.x * dn, a.y * dn, a.z * dn, a.w * dn);
}

// ---------------------------------------------------------------------------
// K5: pull aggregation over prescaled fp16 features:
// out[n] = dinv[n] * sum_e fh[col[e]]   (fh already carries dinv[s]).
// block (24,16): thread = (int2 chunk c of 4 features, row y). 8-deep unroll
// (8 col + 8 int2 gathers in flight). Row = 192 B = 3 cachelines (half of
// fp32). Pure writes; hub row zeroed here (hub_kernel adds after).
// ---------------------------------------------------------------------------
__global__ __launch_bounds__(384)
void pull_kernel(const int2* __restrict__ fh, const float* __restrict__ dinv,
                 const int* __restrict__ rowptr, const int* __restrict__ col,
                 int N, int HUB, float* __restrict__ out) {
    int c = threadIdx.x;                       // 0..23
    int n = blockIdx.x * 16 + threadIdx.y;
    if (n >= N) return;
    float4* out4 = (float4*)out;
    long ob = (long)n * 24 + c;
    if (n == HUB) { out4[ob] = make_float4(0.f, 0.f, 0.f, 0.f); return; }
    int beg = rowptr[n], end = rowptr[n + 1];
    float dn = dinv[n];
    float ax = 0.f, ay = 0.f, az = 0.f, aw = 0.f;
    int e = beg;
    for (; e + 8 <= end; e += 8) {
        int s0 = col[e + 0], s1 = col[e + 1], s2 = col[e + 2], s3 = col[e + 3];
        int s4 = col[e + 4], s5 = col[e + 5], s6 = col[e + 6], s7 = col[e + 7];
        int2 r0 = fh[(long)s0 * 24 + c], r1 = fh[(long)s1 * 24 + c];
        int2 r2 = fh[(long)s2 * 24 + c], r3 = fh[(long)s3 * 24 + c];
        int2 r4 = fh[(long)s4 * 24 + c], r5 = fh[(long)s5 * 24 + c];
        int2 r6 = fh[(long)s6 * 24 + c], r7 = fh[(long)s7 * 24 + c];
        float2 l0 = unpack2(r0.x), h0 = unpack2(r0.y);
        float2 l1 = unpack2(r1.x), h1_ = unpack2(r1.y);
        float2 l2 = unpack2(r2.x), h2 = unpack2(r2.y);
        float2 l3 = unpack2(r3.x), h3 = unpack2(r3.y);
        float2 l4 = unpack2(r4.x), h4 = unpack2(r4.y);
        float2 l5 = unpack2(r5.x), h5 = unpack2(r5.y);
        float2 l6 = unpack2(r6.x), h6 = unpack2(r6.y);
        float2 l7 = unpack2(r7.x), h7 = unpack2(r7.y);
        ax += (l0.x + l1.x) + (l2.x + l3.x) + (l4.x + l5.x) + (l6.x + l7.x);
        ay += (l0.y + l1.y) + (l2.y + l3.y) + (l4.y + l5.y) + (l6.y + l7.y);
        az += (h0.x + h1_.x) + (h2.x + h3.x) + (h4.x + h5.x) + (h6.x + h7.x);
        aw += (h0.y + h1_.y) + (h2.y + h3.y) + (h4.y + h5.y) + (h6.y + h7.y);
    }
    for (; e < end; e++) {
        int s = col[e];
        int2 r = fh[(long)s * 24 + c];
        float2 lo = unpack2(r.x), hi = unpack2(r.y);
        ax += lo.x; ay += lo.y; az += hi.x; aw += hi.y;
    }
    out4[ob] = make_float4(ax * dn, ay * dn, az * dn, aw * dn);
}

// ---------------------------------------------------------------------------
// K6: hub row aggregation (fp16 prescaled): dest[0..95] += dinv[HUB]*sum fh[s]
// over the hub's edges (dest row pre-zeroed by pull_kernel). 256 blocks x 8
// streams, 4-deep unroll, LDS reduce, 96 atomics/block.
// ---------------------------------------------------------------------------
__global__ __launch_bounds__(192)
void hub_kernel(const int2* __restrict__ fh, const float* __restrict__ dinv,
                const int* __restrict__ rowptr, const int* __restrict__ col,
                int HUB, float* __restrict__ dest) {
    int c = threadIdx.x;   // 0..23
    int y = threadIdx.y;   // 0..7
    int beg = rowptr[HUB], end = rowptr[HUB + 1];
    int deg = end - beg;
    int nstr = gridDim.x * 8;
    int sid  = blockIdx.x * 8 + y;
    int chunk = (deg + nstr - 1) / nstr;
    int e  = beg + sid * chunk;
    int e1 = min(e + chunk, end);
    float ax = 0.f, ay = 0.f, az = 0.f, aw = 0.f;
    for (; e + 4 <= e1; e += 4) {
        int s0 = col[e + 0], s1 = col[e + 1], s2 = col[e + 2], s3 = col[e + 3];
        int2 r0 = fh[(long)s0 * 24 + c], r1 = fh[(long)s1 * 24 + c];
        int2 r2 = fh[(long)s2 * 24 + c], r3 = fh[(long)s3 * 24 + c];
        float2 l0 = unpack2(r0.x), h0 = unpack2(r0.y);
        float2 l1 = unpack2(r1.x), h1_ = unpack2(r1.y);
        float2 l2 = unpack2(r2.x), h2 = unpack2(r2.y);
        float2 l3 = unpack2(r3.x), h3 = unpack2(r3.y);
        ax += (l0.x + l1.x) + (l2.x + l3.x);
        ay += (l0.y + l1.y) + (l2.y + l3.y);
        az += (h0.x + h1_.x) + (h2.x + h3.x);
        aw += (h0.y + h1_.y) + (h2.y + h3.y);
    }
    for (; e < e1; e++) {
        int s = col[e];
        int2 r = fh[(long)s * 24 + c];
        float2 lo = unpack2(r.x), hi = unpack2(r.y);
        ax += lo.x; ay += lo.y; az += hi.x; aw += hi.y;
    }
    __shared__ float4 red[8][24];
    red[y][c] = make_float4(ax, ay, az, aw);
    __syncthreads();
    if (y == 0) {
        float4 t = red[0][c];
        #pragma unroll
        for (int k = 1; k < 8; k++) {
            float4 u = red[k][c];
            t.x += u.x; t.y += u.y; t.z += u.z; t.w += u.w;
        }
        float dh = dinv[HUB];
        float* o = dest + 4 * c;
        unsafeAtomicAdd(o + 0, t.x * dh);
        unsafeAtomicAdd(o + 1, t.y * dh);
        unsafeAtomicAdd(o + 2, t.z * dh);
        unsafeAtomicAdd(o + 3, t.w * dh);
    }
}

// ---------------------------------------------------------------------------
// K7: gemm96 — out[N,96] = A @ W + bias (fp32 out, optional relu).
// SAFE IN-PLACE: full 64-row tile staged into LDS behind __syncthreads.
// ---------------------------------------------------------------------------
__global__ __launch_bounds__(192)
void gemm96(const float* __restrict__ A, const float* __restrict__ W,
            const float* __restrict__ bias, float* __restrict__ out,
            int N, int relu) {
    __shared__ float Wl[FD * FD];
    __shared__ float As[64 * 100];
    int t = threadIdx.y * 24 + threadIdx.x;
    {
        const float4* W4 = (const float4*)W;
        float4* Wl4 = (float4*)Wl;
        #pragma unroll 4
        for (int i = t; i < FD * 24; i += 192) Wl4[i] = W4[i];
    }
    int row0 = blockIdx.x * 64;
    int nrows = min(64, N - row0);
    {
        const float4* A4 = (const float4*)(A + (long)row0 * FD);
        for (int i = t; i < nrows * 24; i += 192) {
            int r = i / 24, g = i % 24;
            *(float4*)&As[r * 100 + g * 4] = A4[i];
        }
    }
    __syncthreads();
    int c = threadIdx.x, y = threadIdx.y;
    float acc[8][4];
    #pragma unroll
    for (int j = 0; j < 8; j++)
        #pragma unroll
        for (int i = 0; i < 4; i++) acc[j][i] = 0.f;
    for (int kk = 0; kk < FD; kk += 4) {
        float4 w0 = *(const float4*)&Wl[(kk + 0) * FD + 4 * c];
        float4 w1 = *(const float4*)&Wl[(kk + 1) * FD + 4 * c];
        float4 w2 = *(const float4*)&Wl[(kk + 2) * FD + 4 * c];
        float4 w3 = *(const float4*)&Wl[(kk + 3) * FD + 4 * c];
        #pragma unroll
        for (int j = 0; j < 8; j++) {
            float4 a = *(const float4*)&As[(y + 8 * j) * 100 + kk];
            acc[j][0] = fmaf(a.x, w0.x, fmaf(a.y, w1.x, fmaf(a.z, w2.x, fmaf(a.w, w3.x, acc[j][0]))));
            acc[j][1] = fmaf(a.x, w0.y, fmaf(a.y, w1.y, fmaf(a.z, w2.y, fmaf(a.w, w3.y, acc[j][1]))));
            acc[j][2] = fmaf(a.x, w0.z, fmaf(a.y, w1.z, fmaf(a.z, w2.z, fmaf(a.w, w3.z, acc[j][2]))));
            acc[j][3] = fmaf(a.x, w0.w, fmaf(a.y, w1.w, fmaf(a.z, w2.w, fmaf(a.w, w3.w, acc[j][3]))));
        }
    }
    float4 b4 = *(const float4*)&bias[4 * c];
    #pragma unroll
    for (int j = 0; j < 8; j++) {
        int r = y + 8 * j;
        if (r < nrows) {
            float4 v;
            v.x = acc[j][0] + b4.x; v.y = acc[j][1] + b4.y;
            v.z = acc[j][2] + b4.z; v.w = acc[j][3] + b4.w;
            if (relu) {
                v.x = fmaxf(v.x, 0.f); v.y = fmaxf(v.y, 0.f);
                v.z = fmaxf(v.z, 0.f); v.w = fmaxf(v.w, 0.f);
            }
            *(float4*)&out[(long)(row0 + r) * FD + 4 * c] = v;
        }
    }
}

// ---------------------------------------------------------------------------
// K8: gemm96_h — like gemm96 but epilogue = relu, prescale by dinv[row],
// write fp16 (int2 per thread-row). Output feeds the layer-2 gather.
// ---------------------------------------------------------------------------
__global__ __launch_bounds__(192)
void gemm96_h(const float* __restrict__ A, const float* __restrict__ W,
              const float* __restrict__ bias, const float* __restrict__ dinv,
              int2* __restrict__ out16, int N) {
    __shared__ float Wl[FD * FD];
    __shared__ float As[64 * 100];
    int t = threadIdx.y * 24 + threadIdx.x;
    {
        const float4* W4 = (const float4*)W;
        float4* Wl4 = (float4*)Wl;
        #pragma unroll 4
        for (int i = t; i < FD * 24; i += 192) Wl4[i] = W4[i];
    }
    int row0 = blockIdx.x * 64;
    int nrows = min(64, N - row0);
    {
        const float4* A4 = (const float4*)(A + (long)row0 * FD);
        for (int i = t; i < nrows * 24; i += 192) {
            int r = i / 24, g = i % 24;
            *(float4*)&As[r * 100 + g * 4] = A4[i];
        }
    }
    __syncthreads();
    int c = threadIdx.x, y = threadIdx.y;
    float acc[8][4];
    #pragma unroll
    for (int j = 0; j < 8; j++)
        #pragma unroll
        for (int i = 0; i < 4; i++) acc[j][i] = 0.f;
    for (int kk = 0; kk < FD; kk += 4) {
        float4 w0 = *(const float4*)&Wl[(kk + 0) * FD + 4 * c];
        float4 w1 = *(const float4*)&Wl[(kk + 1) * FD + 4 * c];
        float4 w2 = *(const float4*)&Wl[(kk + 2) * FD + 4 * c];
        float4 w3 = *(const float4*)&Wl[(kk + 3) * FD + 4 * c];
        #pragma unroll
        for (int j = 0; j < 8; j++) {
            float4 a = *(const float4*)&As[(y + 8 * j) * 100 + kk];
            acc[j][0] = fmaf(a.x, w0.x, fmaf(a.y, w1.x, fmaf(a.z, w2.x, fmaf(a.w, w3.x, acc[j][0]))));
            acc[j][1] = fmaf(a.x, w0.y, fmaf(a.y, w1.y, fmaf(a.z, w2.y, fmaf(a.w, w3.y, acc[j][1]))));
            acc[j][2] = fmaf(a.x, w0.z, fmaf(a.y, w1.z, fmaf(a.z, w2.z, fmaf(a.w, w3.z, acc[j][2]))));
            acc[j][3] = fmaf(a.x, w0.w, fmaf(a.y, w1.w, fmaf(a.z, w2.w, fmaf(a.w, w3.w, acc[j][3]))));
        }
    }
    float4 b4 = *(const float4*)&bias[4 * c];
    #pragma unroll
    for (int j = 0; j < 8; j++) {
        int r = y + 8 * j;
        if (r < nrows) {
            float vx = fmaxf(acc[j][0] + b4.x, 0.f);
            float vy = fmaxf(acc[j][1] + b4.y, 0.f);
            float vz = fmaxf(acc[j][2] + b4.z, 0.f);
            float vw = fmaxf(acc[j][3] + b4.w, 0.f);
            float dr = dinv[row0 + r];
            out16[(long)(row0 + r) * 24 + c] = pack4(vx * dr, vy * dr, vz * dr, vw * dr);
        }
    }
}

// ---------------------------------------------------------------------------
// Launch.  (A@X)@W == A@(X@W); gathers run on dinv-prescaled fp16 features.
//   xh  = fp16(dinv*x)          -> mu slot, lower 9.6 MB
//   a0  = A~@x (pull+hub on xh) -> ls slot (fp32)
//   h1h = fp16(dinv*relu(a0@W1+b1)) -> mu slot, upper 9.6 MB   (a0 dead)
//   a1  = A~@h1 (pull+hub on h1h)   -> ls slot (over a0)
//   mu  = a1@W2a+b2a  -> mu slot (xh,h1h dead)
//   ls  = a1@W2b+b2b  -> ls slot (in-place; gemm is tile-local)
// ws: [counts N][perm E][bsum 1024][rowptr N+1][col E][dinv N]  (~7.8 MB)
// ---------------------------------------------------------------------------
extern "C" void kernel_launch(void* const* d_in, const int* in_sizes, int n_in,
                              void* d_out, int out_size, void* d_ws, size_t ws_size,
                              hipStream_t stream) {
    const float* x   = (const float*)d_in[0];
    const float* W1  = (const float*)d_in[1];
    const float* b1  = (const float*)d_in[2];
    const float* W2a = (const float*)d_in[3];
    const float* b2a = (const float*)d_in[4];
    const float* W2b = (const float*)d_in[5];
    const float* b2b = (const float*)d_in[6];
    const int*   ei  = (const int*)d_in[7];

    const int N   = in_sizes[0] / FD;
    const int E   = in_sizes[7] / 2;
    const int HUB = N - 1;
    const int* src = ei;
    const int* dst = ei + E;
    const int NB  = (N + 1023) / 1024;

    int* counts = (int*)d_ws;
    int* perm   = counts + N;
    int* bsum   = perm + E;
    int* rowptr = bsum + 1024;
    int* col    = rowptr + (N + 1);
    float* dinv = (float*)(col + E);

    float* mu_slot = (float*)d_out;
    float* ls_slot = (float*)d_out + (size_t)N * FD;
    int2* xh  = (int2*)mu_slot;                      // N*24 int2 = 9.6 MB
    int2* h1h = (int2*)mu_slot + (size_t)N * 24;     // next 9.6 MB
    float* a0 = ls_slot;
    float* a1 = ls_slot;

    hipMemsetAsync(counts, 0, (size_t)N * sizeof(int), stream);

    // CSR build (reused by both layers)
    deg_kernel  <<<dim3((E + 255) / 256), dim3(256), 0, stream>>>(dst, E, HUB,
                                                                  counts, perm);
    scan_partial<<<dim3(NB), dim3(1024), 0, stream>>>(counts, N, bsum);
    scan_bsum   <<<dim3(1),  dim3(1024), 0, stream>>>(bsum, NB, rowptr, N);
    scan_apply  <<<dim3(NB), dim3(1024), 0, stream>>>(counts, bsum, N, rowptr, dinv);
    fill_kernel <<<dim3((E + 255) / 256), dim3(256), 0, stream>>>(src, dst, perm,
                                                                  rowptr, E, col);
    convert_kernel<<<dim3((N * 24 + 255) / 256), dim3(256), 0, stream>>>(x, dinv,
                                                                         N, xh);

    dim3 pullB(24, 16);
    int  pullG = (N + 15) / 16;
    dim3 hubB(24, 8);
    int  hubG = 256;
    int  gemmG = (N + 63) / 64;
    dim3 gemmB(24, 8);

    // layer 1
    pull_kernel<<<dim3(pullG), pullB, 0, stream>>>(xh, dinv, rowptr, col, N, HUB, a0);
    hub_kernel <<<dim3(hubG),  hubB, 0, stream>>>(xh, dinv, rowptr, col, HUB,
                                                  a0 + (size_t)HUB * FD);
    gemm96_h   <<<dim3(gemmG), gemmB, 0, stream>>>(a0, W1, b1, dinv, h1h, N);

    // layer 2 (aggregation shared by mu and logstd)
    pull_kernel<<<dim3(pullG), pullB, 0, stream>>>(h1h, dinv, rowptr, col, N, HUB, a1);
    hub_kernel <<<dim3(hubG),  hubB, 0, stream>>>(h1h, dinv, rowptr, col, HUB,
                                                  a1 + (size_t)HUB * FD);
    gemm96<<<dim3(gemmG), gemmB, 0, stream>>>(a1, W2a, b2a, mu_slot, N, 0);
    gemm96<<<dim3(gemmG), gemmB, 0, stream>>>(a1, W2b, b2b, ls_slot, N, 0);  // in-place
}

// Round 9
// 340.456 us; speedup vs baseline: 1.3781x; 1.0253x over previous
//
#include <hip/hip_runtime.h>
#include <hip/hip_fp16.h>

#define FD 96   // feature dim

// ---- fp16 pack/unpack helpers (4 halves in an int2) -----------------------
__device__ inline float2 unpack2(int v) {
    __half2 h = *reinterpret_cast<__half2*>(&v);
    return __half22float2(h);
}
__device__ inline int2 pack4(float a, float b, float c, float d) {
    __half2 lo = __floats2half2_rn(a, b);
    __half2 hi = __floats2half2_rn(c, d);
    int2 r;
    r.x = *reinterpret_cast<int*>(&lo);
    r.y = *reinterpret_cast<int*>(&hi);
    return r;
}
// load 4 fp16 (int2) from LDS -> float4
__device__ inline float4 lds_w4(const __half* Wl, int k, int c4) {
    int2 wv = *(const int2*)&Wl[k * FD + c4];
    float2 lo = unpack2(wv.x), hi = unpack2(wv.y);
    return make_float4(lo.x, lo.y, hi.x, hi.y);
}

// ---------------------------------------------------------------------------
// K1: degree histogram + per-edge rank capture (perm). Hub via ballot.
// ---------------------------------------------------------------------------
__global__ void deg_kernel(const int* __restrict__ dst, int E, int HUB,
                           int* __restrict__ counts, int* __restrict__ perm) {
    int e = blockIdx.x * 256 + threadIdx.x;
    int d = (e < E) ? dst[e] : -1;
    bool isHub = (d == HUB);
    unsigned long long m = __ballot(isHub);
    if (isHub) {
        int lane = threadIdx.x & 63;
        int leader = __ffsll((unsigned long long)m) - 1;
        int base = 0;
        if (lane == leader) base = atomicAdd(&counts[HUB], (int)__popcll(m));
        base = __shfl(base, leader);
        unsigned long long below = m & ((1ull << lane) - 1ull);
        perm[e] = base + (int)__popcll(below);
    } else if (d >= 0) {
        perm[e] = atomicAdd(&counts[d], 1);
    }
}

// ---------------------------------------------------------------------------
// K2a: per-1024-chunk partial sums of counts -> bsum[block]
// ---------------------------------------------------------------------------
__global__ __launch_bounds__(1024)
void scan_partial(const int* __restrict__ counts, int N, int* __restrict__ bsum) {
    int i = blockIdx.x * 1024 + threadIdx.x;
    int v = (i < N) ? counts[i] : 0;
    #pragma unroll
    for (int off = 32; off; off >>= 1) v += __shfl_down(v, off);
    __shared__ int ws_[16];
    int t = threadIdx.x;
    if ((t & 63) == 0) ws_[t >> 6] = v;
    __syncthreads();
    if (t == 0) {
        int s = 0;
        #pragma unroll
        for (int k = 0; k < 16; k++) s += ws_[k];
        bsum[blockIdx.x] = s;
    }
}

// ---------------------------------------------------------------------------
// K2b: single-block exclusive scan of bsum[NB]; grand total -> rowptr[N].
// ---------------------------------------------------------------------------
__global__ __launch_bounds__(1024)
void scan_bsum(int* __restrict__ bsum, int NB, int* __restrict__ rowptr, int N) {
    int t = threadIdx.x, lane = t & 63, wv = t >> 6;
    int v = (t < NB) ? bsum[t] : 0;
    int x = v;
    #pragma unroll
    for (int off = 1; off < 64; off <<= 1) {
        int u = __shfl_up(x, off);
        if (lane >= off) x += u;
    }
    __shared__ int wsum[16];
    if (lane == 63) wsum[wv] = x;
    __syncthreads();
    if (wv == 0 && lane < 16) {
        int w = wsum[lane];
        #pragma unroll
        for (int off = 1; off < 16; off <<= 1) {
            int u = __shfl_up(w, off);
            if (lane >= off) w += u;
        }
        wsum[lane] = w;
    }
    __syncthreads();
    int waveoff = (wv == 0) ? 0 : wsum[wv - 1];
    int incl = waveoff + x;
    if (t < NB) bsum[t] = incl - v;
    if (t == 1023) rowptr[N] = incl;
}

// ---------------------------------------------------------------------------
// K2c: apply scan -> rowptr[i]; ALSO emits dinv[i] (fused).
// ---------------------------------------------------------------------------
__global__ __launch_bounds__(1024)
void scan_apply(const int* __restrict__ counts, const int* __restrict__ bsum,
                int N, int* __restrict__ rowptr, float* __restrict__ dinv) {
    int i = blockIdx.x * 1024 + threadIdx.x;
    int t = threadIdx.x, lane = t & 63, wv = t >> 6;
    int v = (i < N) ? counts[i] : 0;
    int x = v;
    #pragma unroll
    for (int off = 1; off < 64; off <<= 1) {
        int u = __shfl_up(x, off);
        if (lane >= off) x += u;
    }
    __shared__ int wsum[16];
    if (lane == 63) wsum[wv] = x;
    __syncthreads();
    if (wv == 0 && lane < 16) {
        int w = wsum[lane];
        #pragma unroll
        for (int off = 1; off < 16; off <<= 1) {
            int u = __shfl_up(w, off);
            if (lane >= off) w += u;
        }
        wsum[lane] = w;
    }
    __syncthreads();
    int waveoff = (wv == 0) ? 0 : wsum[wv - 1];
    if (i < N) {
        rowptr[i] = bsum[blockIdx.x] + waveoff + x - v;
        float d = (float)v;
        dinv[i] = (d > 0.f) ? rsqrtf(fmaxf(d, 1.f)) : 0.f;
    }
}

// ---------------------------------------------------------------------------
// K3: fill CSR col[] — atomic-free (rank precomputed in perm[]).
// ---------------------------------------------------------------------------
__global__ void fill_kernel(const int* __restrict__ src, const int* __restrict__ dst,
                            const int* __restrict__ perm,
                            const int* __restrict__ rowptr, int E,
                            int* __restrict__ col) {
    int e = blockIdx.x * 256 + threadIdx.x;
    if (e >= E) return;
    int d = dst[e];
    col[rowptr[d] + perm[e]] = src[e];
}

// ---------------------------------------------------------------------------
// K4: convert — xh[n] = fp16(dinv[n] * x[n])  (prescaled fp16 features).
// ---------------------------------------------------------------------------
__global__ void convert_kernel(const float* __restrict__ x,
                               const float* __restrict__ dinv, int N,
                               int2* __restrict__ xh) {
    int i = blockIdx.x * 256 + threadIdx.x;
    if (i >= N * 24) return;
    int n = i / 24;
    float dn = dinv[n];
    float4 a = ((const float4*)x)[i];
    xh[i] = pack4(a.x * dn, a.y * dn, a.z * dn, a.w * dn);
}

// ---------------------------------------------------------------------------
// K5: pull aggregation over prescaled fp16 features (line-transaction bound:
// 2 x 128B lines per edge). 8-deep unrolled gathers for MLP. Pure writes.
// ---------------------------------------------------------------------------
__global__ __launch_bounds__(384)
void pull_kernel(const int2* __restrict__ fh, const float* __restrict__ dinv,
                 const int* __restrict__ rowptr, const int* __restrict__ col,
                 int N, int HUB, float* __restrict__ out) {
    int c = threadIdx.x;                       // 0..23
    int n = blockIdx.x * 16 + threadIdx.y;
    if (n >= N) return;
    float4* out4 = (float4*)out;
    long ob = (long)n * 24 + c;
    if (n == HUB) { out4[ob] = make_float4(0.f, 0.f, 0.f, 0.f); return; }
    int beg = rowptr[n], end = rowptr[n + 1];
    float dn = dinv[n];
    float ax = 0.f, ay = 0.f, az = 0.f, aw = 0.f;
    int e = beg;
    for (; e + 8 <= end; e += 8) {
        int s0 = col[e + 0], s1 = col[e + 1], s2 = col[e + 2], s3 = col[e + 3];
        int s4 = col[e + 4], s5 = col[e + 5], s6 = col[e + 6], s7 = col[e + 7];
        int2 r0 = fh[(long)s0 * 24 + c], r1 = fh[(long)s1 * 24 + c];
        int2 r2 = fh[(long)s2 * 24 + c], r3 = fh[(long)s3 * 24 + c];
        int2 r4 = fh[(long)s4 * 24 + c], r5 = fh[(long)s5 * 24 + c];
        int2 r6 = fh[(long)s6 * 24 + c], r7 = fh[(long)s7 * 24 + c];
        float2 l0 = unpack2(r0.x), h0 = unpack2(r0.y);
        float2 l1 = unpack2(r1.x), h1_ = unpack2(r1.y);
        float2 l2 = unpack2(r2.x), h2 = unpack2(r2.y);
        float2 l3 = unpack2(r3.x), h3 = unpack2(r3.y);
        float2 l4 = unpack2(r4.x), h4 = unpack2(r4.y);
        float2 l5 = unpack2(r5.x), h5 = unpack2(r5.y);
        float2 l6 = unpack2(r6.x), h6 = unpack2(r6.y);
        float2 l7 = unpack2(r7.x), h7 = unpack2(r7.y);
        ax += (l0.x + l1.x) + (l2.x + l3.x) + (l4.x + l5.x) + (l6.x + l7.x);
        ay += (l0.y + l1.y) + (l2.y + l3.y) + (l4.y + l5.y) + (l6.y + l7.y);
        az += (h0.x + h1_.x) + (h2.x + h3.x) + (h4.x + h5.x) + (h6.x + h7.x);
        aw += (h0.y + h1_.y) + (h2.y + h3.y) + (h4.y + h5.y) + (h6.y + h7.y);
    }
    for (; e < end; e++) {
        int s = col[e];
        int2 r = fh[(long)s * 24 + c];
        float2 lo = unpack2(r.x), hi = unpack2(r.y);
        ax += lo.x; ay += lo.y; az += hi.x; aw += hi.y;
    }
    out4[ob] = make_float4(ax * dn, ay * dn, az * dn, aw * dn);
}

// ---------------------------------------------------------------------------
// K6: hub row aggregation (fp16 prescaled): dest[0..95] += dinv[HUB]*sum fh[s]
// (dest row pre-zeroed by pull_kernel). 256 blocks x 8 streams, LDS reduce.
// ---------------------------------------------------------------------------
__global__ __launch_bounds__(192)
void hub_kernel(const int2* __restrict__ fh, const float* __restrict__ dinv,
                const int* __restrict__ rowptr, const int* __restrict__ col,
                int HUB, float* __restrict__ dest) {
    int c = threadIdx.x;   // 0..23
    int y = threadIdx.y;   // 0..7
    int beg = rowptr[HUB], end = rowptr[HUB + 1];
    int deg = end - beg;
    int nstr = gridDim.x * 8;
    int sid  = blockIdx.x * 8 + y;
    int chunk = (deg + nstr - 1) / nstr;
    int e  = beg + sid * chunk;
    int e1 = min(e + chunk, end);
    float ax = 0.f, ay = 0.f, az = 0.f, aw = 0.f;
    for (; e + 4 <= e1; e += 4) {
        int s0 = col[e + 0], s1 = col[e + 1], s2 = col[e + 2], s3 = col[e + 3];
        int2 r0 = fh[(long)s0 * 24 + c], r1 = fh[(long)s1 * 24 + c];
        int2 r2 = fh[(long)s2 * 24 + c], r3 = fh[(long)s3 * 24 + c];
        float2 l0 = unpack2(r0.x), h0 = unpack2(r0.y);
        float2 l1 = unpack2(r1.x), h1_ = unpack2(r1.y);
        float2 l2 = unpack2(r2.x), h2 = unpack2(r2.y);
        float2 l3 = unpack2(r3.x), h3 = unpack2(r3.y);
        ax += (l0.x + l1.x) + (l2.x + l3.x);
        ay += (l0.y + l1.y) + (l2.y + l3.y);
        az += (h0.x + h1_.x) + (h2.x + h3.x);
        aw += (h0.y + h1_.y) + (h2.y + h3.y);
    }
    for (; e < e1; e++) {
        int s = col[e];
        int2 r = fh[(long)s * 24 + c];
        float2 lo = unpack2(r.x), hi = unpack2(r.y);
        ax += lo.x; ay += lo.y; az += hi.x; aw += hi.y;
    }
    __shared__ float4 red[8][24];
    red[y][c] = make_float4(ax, ay, az, aw);
    __syncthreads();
    if (y == 0) {
        float4 t = red[0][c];
        #pragma unroll
        for (int k = 1; k < 8; k++) {
            float4 u = red[k][c];
            t.x += u.x; t.y += u.y; t.z += u.z; t.w += u.w;
        }
        float dh = dinv[HUB];
        float* o = dest + 4 * c;
        unsafeAtomicAdd(o + 0, t.x * dh);
        unsafeAtomicAdd(o + 1, t.y * dh);
        unsafeAtomicAdd(o + 2, t.z * dh);
        unsafeAtomicAdd(o + 3, t.w * dh);
    }
}

// ---------------------------------------------------------------------------
// K7: gemm96_h — h1h = fp16(dinv*relu(A@W1+b1)). W staged as fp16 in LDS
// (18.4 KB + As 25.6 KB = 44 KB -> 3 blocks/CU vs 2 before).
// ---------------------------------------------------------------------------
__global__ __launch_bounds__(192)
void gemm96_h(const float* __restrict__ A, const float* __restrict__ W,
              const float* __restrict__ bias, const float* __restrict__ dinv,
              int2* __restrict__ out16, int N) {
    __shared__ __half Wl[FD * FD];       // 18432 B (fp16)
    __shared__ float As[64 * 100];       // 25600 B
    int t = threadIdx.y * 24 + threadIdx.x;
    {   // stage W fp32 -> fp16
        const float4* W4 = (const float4*)W;
        #pragma unroll 4
        for (int i = t; i < FD * 24; i += 192) {
            float4 w = W4[i];
            *(int2*)&Wl[i * 4] = pack4(w.x, w.y, w.z, w.w);
        }
    }
    int row0 = blockIdx.x * 64;
    int nrows = min(64, N - row0);
    {
        const float4* A4 = (const float4*)(A + (long)row0 * FD);
        for (int i = t; i < nrows * 24; i += 192) {
            int r = i / 24, g = i % 24;
            *(float4*)&As[r * 100 + g * 4] = A4[i];
        }
    }
    __syncthreads();
    int c = threadIdx.x, y = threadIdx.y;
    float acc[8][4];
    #pragma unroll
    for (int j = 0; j < 8; j++)
        #pragma unroll
        for (int i = 0; i < 4; i++) acc[j][i] = 0.f;
    for (int kk = 0; kk < FD; kk += 4) {
        float4 w0 = lds_w4(Wl, kk + 0, 4 * c);
        float4 w1 = lds_w4(Wl, kk + 1, 4 * c);
        float4 w2 = lds_w4(Wl, kk + 2, 4 * c);
        float4 w3 = lds_w4(Wl, kk + 3, 4 * c);
        #pragma unroll
        for (int j = 0; j < 8; j++) {
            float4 a = *(const float4*)&As[(y + 8 * j) * 100 + kk];
            acc[j][0] = fmaf(a.x, w0.x, fmaf(a.y, w1.x, fmaf(a.z, w2.x, fmaf(a.w, w3.x, acc[j][0]))));
            acc[j][1] = fmaf(a.x, w0.y, fmaf(a.y, w1.y, fmaf(a.z, w2.y, fmaf(a.w, w3.y, acc[j][1]))));
            acc[j][2] = fmaf(a.x, w0.z, fmaf(a.y, w1.z, fmaf(a.z, w2.z, fmaf(a.w, w3.z, acc[j][2]))));
            acc[j][3] = fmaf(a.x, w0.w, fmaf(a.y, w1.w, fmaf(a.z, w2.w, fmaf(a.w, w3.w, acc[j][3]))));
        }
    }
    float4 b4 = *(const float4*)&bias[4 * c];
    #pragma unroll
    for (int j = 0; j < 8; j++) {
        int r = y + 8 * j;
        if (r < nrows) {
            float vx = fmaxf(acc[j][0] + b4.x, 0.f);
            float vy = fmaxf(acc[j][1] + b4.y, 0.f);
            float vz = fmaxf(acc[j][2] + b4.z, 0.f);
            float vw = fmaxf(acc[j][3] + b4.w, 0.f);
            float dr = dinv[row0 + r];
            out16[(long)(row0 + r) * 24 + c] = pack4(vx * dr, vy * dr, vz * dr, vw * dr);
        }
    }
}

// ---------------------------------------------------------------------------
// K8: gemm96_dual — mu = A@Wa+ba, ls = A@Wb+bb from ONE A-tile staging.
// Both W staged fp16 (2x18.4 KB) + As 25.6 KB = 62.5 KB -> 2 blocks/CU.
// SAFE IN-PLACE for ls (tile fully staged behind __syncthreads).
// ---------------------------------------------------------------------------
__global__ __launch_bounds__(192)
void gemm96_dual(const float* __restrict__ A,
                 const float* __restrict__ Wa, const float* __restrict__ ba,
                 const float* __restrict__ Wb, const float* __restrict__ bb,
                 float* __restrict__ mu, float* __restrict__ ls, int N) {
    __shared__ __half Wla[FD * FD];      // 18432 B
    __shared__ __half Wlb[FD * FD];      // 18432 B
    __shared__ float As[64 * 100];       // 25600 B
    int t = threadIdx.y * 24 + threadIdx.x;
    {
        const float4* Wa4 = (const float4*)Wa;
        const float4* Wb4 = (const float4*)Wb;
        #pragma unroll 4
        for (int i = t; i < FD * 24; i += 192) {
            float4 w = Wa4[i];
            *(int2*)&Wla[i * 4] = pack4(w.x, w.y, w.z, w.w);
            float4 v = Wb4[i];
            *(int2*)&Wlb[i * 4] = pack4(v.x, v.y, v.z, v.w);
        }
    }
    int row0 = blockIdx.x * 64;
    int nrows = min(64, N - row0);
    {
        const float4* A4 = (const float4*)(A + (long)row0 * FD);
        for (int i = t; i < nrows * 24; i += 192) {
            int r = i / 24, g = i % 24;
            *(float4*)&As[r * 100 + g * 4] = A4[i];
        }
    }
    __syncthreads();
    int c = threadIdx.x, y = threadIdx.y;
    float acca[8][4], accb[8][4];
    #pragma unroll
    for (int j = 0; j < 8; j++)
        #pragma unroll
        for (int i = 0; i < 4; i++) { acca[j][i] = 0.f; accb[j][i] = 0.f; }

    for (int kk = 0; kk < FD; kk += 4) {
        float4 wa0 = lds_w4(Wla, kk + 0, 4 * c);
        float4 wa1 = lds_w4(Wla, kk + 1, 4 * c);
        float4 wa2 = lds_w4(Wla, kk + 2, 4 * c);
        float4 wa3 = lds_w4(Wla, kk + 3, 4 * c);
        float4 wb0 = lds_w4(Wlb, kk + 0, 4 * c);
        float4 wb1 = lds_w4(Wlb, kk + 1, 4 * c);
        float4 wb2 = lds_w4(Wlb, kk + 2, 4 * c);
        float4 wb3 = lds_w4(Wlb, kk + 3, 4 * c);
        #pragma unroll
        for (int j = 0; j < 8; j++) {
            float4 a = *(const float4*)&As[(y + 8 * j) * 100 + kk];
            acca[j][0] = fmaf(a.x, wa0.x, fmaf(a.y, wa1.x, fmaf(a.z, wa2.x, fmaf(a.w, wa3.x, acca[j][0]))));
            acca[j][1] = fmaf(a.x, wa0.y, fmaf(a.y, wa1.y, fmaf(a.z, wa2.y, fmaf(a.w, wa3.y, acca[j][1]))));
            acca[j][2] = fmaf(a.x, wa0.z, fmaf(a.y, wa1.z, fmaf(a.z, wa2.z, fmaf(a.w, wa3.z, acca[j][2]))));
            acca[j][3] = fmaf(a.x, wa0.w, fmaf(a.y, wa1.w, fmaf(a.z, wa2.w, fmaf(a.w, wa3.w, acca[j][3]))));
            accb[j][0] = fmaf(a.x, wb0.x, fmaf(a.y, wb1.x, fmaf(a.z, wb2.x, fmaf(a.w, wb3.x, accb[j][0]))));
            accb[j][1] = fmaf(a.x, wb0.y, fmaf(a.y, wb1.y, fmaf(a.z, wb2.y, fmaf(a.w, wb3.y, accb[j][1]))));
            accb[j][2] = fmaf(a.x, wb0.z, fmaf(a.y, wb1.z, fmaf(a.z, wb2.z, fmaf(a.w, wb3.z, accb[j][2]))));
            accb[j][3] = fmaf(a.x, wb0.w, fmaf(a.y, wb1.w, fmaf(a.z, wb2.w, fmaf(a.w, wb3.w, accb[j][3]))));
        }
    }
    float4 ba4 = *(const float4*)&ba[4 * c];
    float4 bb4 = *(const float4*)&bb[4 * c];
    #pragma unroll
    for (int j = 0; j < 8; j++) {
        int r = y + 8 * j;
        if (r < nrows) {
            float4 va, vb;
            va.x = acca[j][0] + ba4.x; va.y = acca[j][1] + ba4.y;
            va.z = acca[j][2] + ba4.z; va.w = acca[j][3] + ba4.w;
            vb.x = accb[j][0] + bb4.x; vb.y = accb[j][1] + bb4.y;
            vb.z = accb[j][2] + bb4.z; vb.w = accb[j][3] + bb4.w;
            *(float4*)&mu[(long)(row0 + r) * FD + 4 * c] = va;
            *(float4*)&ls[(long)(row0 + r) * FD + 4 * c] = vb;
        }
    }
}

// ---------------------------------------------------------------------------
// Launch.  (A@X)@W == A@(X@W); gathers on dinv-prescaled fp16 features.
//   xh  = fp16(dinv*x)              -> mu slot, lower 9.6 MB
//   a0  = agg(xh)  (pull+hub)       -> ls slot (fp32)
//   h1h = fp16(dinv*relu(a0@W1+b1)) -> mu slot, upper 9.6 MB  (a0 dead)
//   a1  = agg(h1h) (pull+hub)       -> ls slot (over a0)
//   mu,ls = dual-gemm(a1)           -> mu slot + ls slot (in-place over a1)
// ws: [counts N][perm E][bsum 1024][rowptr N+1][col E][dinv N]  (~7.8 MB)
// ---------------------------------------------------------------------------
extern "C" void kernel_launch(void* const* d_in, const int* in_sizes, int n_in,
                              void* d_out, int out_size, void* d_ws, size_t ws_size,
                              hipStream_t stream) {
    const float* x   = (const float*)d_in[0];
    const float* W1  = (const float*)d_in[1];
    const float* b1  = (const float*)d_in[2];
    const float* W2a = (const float*)d_in[3];
    const float* b2a = (const float*)d_in[4];
    const float* W2b = (const float*)d_in[5];
    const float* b2b = (const float*)d_in[6];
    const int*   ei  = (const int*)d_in[7];

    const int N   = in_sizes[0] / FD;
    const int E   = in_sizes[7] / 2;
    const int HUB = N - 1;
    const int* src = ei;
    const int* dst = ei + E;
    const int NB  = (N + 1023) / 1024;

    int* counts = (int*)d_ws;
    int* perm   = counts + N;
    int* bsum   = perm + E;
    int* rowptr = bsum + 1024;
    int* col    = rowptr + (N + 1);
    float* dinv = (float*)(col + E);

    float* mu_slot = (float*)d_out;
    float* ls_slot = (float*)d_out + (size_t)N * FD;
    int2* xh  = (int2*)mu_slot;                      // N*24 int2 = 9.6 MB
    int2* h1h = (int2*)mu_slot + (size_t)N * 24;     // next 9.6 MB
    float* a0 = ls_slot;
    float* a1 = ls_slot;

    hipMemsetAsync(counts, 0, (size_t)N * sizeof(int), stream);

    // CSR build (reused by both layers)
    deg_kernel  <<<dim3((E + 255) / 256), dim3(256), 0, stream>>>(dst, E, HUB,
                                                                  counts, perm);
    scan_partial<<<dim3(NB), dim3(1024), 0, stream>>>(counts, N, bsum);
    scan_bsum   <<<dim3(1),  dim3(1024), 0, stream>>>(bsum, NB, rowptr, N);
    scan_apply  <<<dim3(NB), dim3(1024), 0, stream>>>(counts, bsum, N, rowptr, dinv);
    fill_kernel <<<dim3((E + 255) / 256), dim3(256), 0, stream>>>(src, dst, perm,
                                                                  rowptr, E, col);
    convert_kernel<<<dim3((N * 24 + 255) / 256), dim3(256), 0, stream>>>(x, dinv,
                                                                         N, xh);

    dim3 pullB(24, 16);
    int  pullG = (N + 15) / 16;
    dim3 hubB(24, 8);
    int  hubG = 256;
    int  gemmG = (N + 63) / 64;
    dim3 gemmB(24, 8);

    // layer 1
    pull_kernel<<<dim3(pullG), pullB, 0, stream>>>(xh, dinv, rowptr, col, N, HUB, a0);
    hub_kernel <<<dim3(hubG),  hubB, 0, stream>>>(xh, dinv, rowptr, col, HUB,
                                                  a0 + (size_t)HUB * FD);
    gemm96_h   <<<dim3(gemmG), gemmB, 0, stream>>>(a0, W1, b1, dinv, h1h, N);

    // layer 2 (aggregation + BOTH output GEMMs share one staging)
    pull_kernel<<<dim3(pullG), pullB, 0, stream>>>(h1h, dinv, rowptr, col, N, HUB, a1);
    hub_kernel <<<dim3(hubG),  hubB, 0, stream>>>(h1h, dinv, rowptr, col, HUB,
                                                  a1 + (size_t)HUB * FD);
    gemm96_dual<<<dim3(gemmG), gemmB, 0, stream>>>(a1, W2a, b2a, W2b, b2b,
                                                   mu_slot, ls_slot, N);
}

// Round 10
// 307.998 us; speedup vs baseline: 1.5233x; 1.1054x over previous
//
#include <hip/hip_runtime.h>
#include <hip/hip_fp16.h>

#define FD 96   // feature dim

typedef _Float16 f16x8 __attribute__((ext_vector_type(8)));
typedef float f32x4 __attribute__((ext_vector_type(4)));

// ---- fp16 pack/unpack helpers (4 halves in an int2) -----------------------
__device__ inline float2 unpack2(int v) {
    __half2 h = *reinterpret_cast<__half2*>(&v);
    return __half22float2(h);
}
__device__ inline int2 pack4(float a, float b, float c, float d) {
    __half2 lo = __floats2half2_rn(a, b);
    __half2 hi = __floats2half2_rn(c, d);
    int2 r;
    r.x = *reinterpret_cast<int*>(&lo);
    r.y = *reinterpret_cast<int*>(&hi);
    return r;
}
// load 4 fp16 (int2) from LDS -> float4
__device__ inline float4 lds_w4(const __half* Wl, int k, int c4) {
    int2 wv = *(const int2*)&Wl[k * FD + c4];
    float2 lo = unpack2(wv.x), hi = unpack2(wv.y);
    return make_float4(lo.x, lo.y, hi.x, hi.y);
}

// ---------------------------------------------------------------------------
// K1: degree histogram + per-edge rank capture (perm). Hub via ballot.
// ---------------------------------------------------------------------------
__global__ void deg_kernel(const int* __restrict__ dst, int E, int HUB,
                           int* __restrict__ counts, int* __restrict__ perm) {
    int e = blockIdx.x * 256 + threadIdx.x;
    int d = (e < E) ? dst[e] : -1;
    bool isHub = (d == HUB);
    unsigned long long m = __ballot(isHub);
    if (isHub) {
        int lane = threadIdx.x & 63;
        int leader = __ffsll((unsigned long long)m) - 1;
        int base = 0;
        if (lane == leader) base = atomicAdd(&counts[HUB], (int)__popcll(m));
        base = __shfl(base, leader);
        unsigned long long below = m & ((1ull << lane) - 1ull);
        perm[e] = base + (int)__popcll(below);
    } else if (d >= 0) {
        perm[e] = atomicAdd(&counts[d], 1);
    }
}

// ---------------------------------------------------------------------------
// K2a: per-1024-chunk partial sums of counts -> bsum[block]
// ---------------------------------------------------------------------------
__global__ __launch_bounds__(1024)
void scan_partial(const int* __restrict__ counts, int N, int* __restrict__ bsum) {
    int i = blockIdx.x * 1024 + threadIdx.x;
    int v = (i < N) ? counts[i] : 0;
    #pragma unroll
    for (int off = 32; off; off >>= 1) v += __shfl_down(v, off);
    __shared__ int ws_[16];
    int t = threadIdx.x;
    if ((t & 63) == 0) ws_[t >> 6] = v;
    __syncthreads();
    if (t == 0) {
        int s = 0;
        #pragma unroll
        for (int k = 0; k < 16; k++) s += ws_[k];
        bsum[blockIdx.x] = s;
    }
}

// ---------------------------------------------------------------------------
// K2b: single-block exclusive scan of bsum[NB]; grand total -> rowptr[N].
// ---------------------------------------------------------------------------
__global__ __launch_bounds__(1024)
void scan_bsum(int* __restrict__ bsum, int NB, int* __restrict__ rowptr, int N) {
    int t = threadIdx.x, lane = t & 63, wv = t >> 6;
    int v = (t < NB) ? bsum[t] : 0;
    int x = v;
    #pragma unroll
    for (int off = 1; off < 64; off <<= 1) {
        int u = __shfl_up(x, off);
        if (lane >= off) x += u;
    }
    __shared__ int wsum[16];
    if (lane == 63) wsum[wv] = x;
    __syncthreads();
    if (wv == 0 && lane < 16) {
        int w = wsum[lane];
        #pragma unroll
        for (int off = 1; off < 16; off <<= 1) {
            int u = __shfl_up(w, off);
            if (lane >= off) w += u;
        }
        wsum[lane] = w;
    }
    __syncthreads();
    int waveoff = (wv == 0) ? 0 : wsum[wv - 1];
    int incl = waveoff + x;
    if (t < NB) bsum[t] = incl - v;
    if (t == 1023) rowptr[N] = incl;
}

// ---------------------------------------------------------------------------
// K2c: apply scan -> rowptr[i]; ALSO emits dinv[i] (fused).
// ---------------------------------------------------------------------------
__global__ __launch_bounds__(1024)
void scan_apply(const int* __restrict__ counts, const int* __restrict__ bsum,
                int N, int* __restrict__ rowptr, float* __restrict__ dinv) {
    int i = blockIdx.x * 1024 + threadIdx.x;
    int t = threadIdx.x, lane = t & 63, wv = t >> 6;
    int v = (i < N) ? counts[i] : 0;
    int x = v;
    #pragma unroll
    for (int off = 1; off < 64; off <<= 1) {
        int u = __shfl_up(x, off);
        if (lane >= off) x += u;
    }
    __shared__ int wsum[16];
    if (lane == 63) wsum[wv] = x;
    __syncthreads();
    if (wv == 0 && lane < 16) {
        int w = wsum[lane];
        #pragma unroll
        for (int off = 1; off < 16; off <<= 1) {
            int u = __shfl_up(w, off);
            if (lane >= off) w += u;
        }
        wsum[lane] = w;
    }
    __syncthreads();
    int waveoff = (wv == 0) ? 0 : wsum[wv - 1];
    if (i < N) {
        rowptr[i] = bsum[blockIdx.x] + waveoff + x - v;
        float d = (float)v;
        dinv[i] = (d > 0.f) ? rsqrtf(fmaxf(d, 1.f)) : 0.f;
    }
}

// ---------------------------------------------------------------------------
// K3: fill CSR col[] — atomic-free (rank precomputed in perm[]).
// ---------------------------------------------------------------------------
__global__ void fill_kernel(const int* __restrict__ src, const int* __restrict__ dst,
                            const int* __restrict__ perm,
                            const int* __restrict__ rowptr, int E,
                            int* __restrict__ col) {
    int e = blockIdx.x * 256 + threadIdx.x;
    if (e >= E) return;
    int d = dst[e];
    col[rowptr[d] + perm[e]] = src[e];
}

// ---------------------------------------------------------------------------
// K4: convert — xh[n] = fp16(dinv[n] * x[n])  (prescaled fp16 features).
// ---------------------------------------------------------------------------
__global__ void convert_kernel(const float* __restrict__ x,
                               const float* __restrict__ dinv, int N,
                               int2* __restrict__ xh) {
    int i = blockIdx.x * 256 + threadIdx.x;
    if (i >= N * 24) return;
    int n = i / 24;
    float dn = dinv[n];
    float4 a = ((const float4*)x)[i];
    xh[i] = pack4(a.x * dn, a.y * dn, a.z * dn, a.w * dn);
}

// ---------------------------------------------------------------------------
// K4b: wt_kernel — Wta[n][k] = fp16(Wa[k][n]), Wtb likewise (transposed fp16
// weights in MFMA B-fragment-friendly layout).
// ---------------------------------------------------------------------------
__global__ void wt_kernel(const float* __restrict__ Wa, const float* __restrict__ Wb,
                          __half* __restrict__ Wta, __half* __restrict__ Wtb) {
    int i = blockIdx.x * 256 + threadIdx.x;
    if (i >= FD * FD) return;
    int n = i / FD, k = i % FD;
    Wta[i] = __float2half(Wa[k * FD + n]);
    Wtb[i] = __float2half(Wb[k * FD + n]);
}

// ---------------------------------------------------------------------------
// K5: pull aggregation over prescaled fp16 features, fp32 output (layer 1).
// ---------------------------------------------------------------------------
__global__ __launch_bounds__(384)
void pull_kernel(const int2* __restrict__ fh, const float* __restrict__ dinv,
                 const int* __restrict__ rowptr, const int* __restrict__ col,
                 int N, int HUB, float* __restrict__ out) {
    int c = threadIdx.x;                       // 0..23
    int n = blockIdx.x * 16 + threadIdx.y;
    if (n >= N) return;
    float4* out4 = (float4*)out;
    long ob = (long)n * 24 + c;
    if (n == HUB) { out4[ob] = make_float4(0.f, 0.f, 0.f, 0.f); return; }
    int beg = rowptr[n], end = rowptr[n + 1];
    float dn = dinv[n];
    float ax = 0.f, ay = 0.f, az = 0.f, aw = 0.f;
    int e = beg;
    for (; e + 8 <= end; e += 8) {
        int s0 = col[e + 0], s1 = col[e + 1], s2 = col[e + 2], s3 = col[e + 3];
        int s4 = col[e + 4], s5 = col[e + 5], s6 = col[e + 6], s7 = col[e + 7];
        int2 r0 = fh[(long)s0 * 24 + c], r1 = fh[(long)s1 * 24 + c];
        int2 r2 = fh[(long)s2 * 24 + c], r3 = fh[(long)s3 * 24 + c];
        int2 r4 = fh[(long)s4 * 24 + c], r5 = fh[(long)s5 * 24 + c];
        int2 r6 = fh[(long)s6 * 24 + c], r7 = fh[(long)s7 * 24 + c];
        float2 l0 = unpack2(r0.x), h0 = unpack2(r0.y);
        float2 l1 = unpack2(r1.x), h1_ = unpack2(r1.y);
        float2 l2 = unpack2(r2.x), h2 = unpack2(r2.y);
        float2 l3 = unpack2(r3.x), h3 = unpack2(r3.y);
        float2 l4 = unpack2(r4.x), h4 = unpack2(r4.y);
        float2 l5 = unpack2(r5.x), h5 = unpack2(r5.y);
        float2 l6 = unpack2(r6.x), h6 = unpack2(r6.y);
        float2 l7 = unpack2(r7.x), h7 = unpack2(r7.y);
        ax += (l0.x + l1.x) + (l2.x + l3.x) + (l4.x + l5.x) + (l6.x + l7.x);
        ay += (l0.y + l1.y) + (l2.y + l3.y) + (l4.y + l5.y) + (l6.y + l7.y);
        az += (h0.x + h1_.x) + (h2.x + h3.x) + (h4.x + h5.x) + (h6.x + h7.x);
        aw += (h0.y + h1_.y) + (h2.y + h3.y) + (h4.y + h5.y) + (h6.y + h7.y);
    }
    for (; e < end; e++) {
        int s = col[e];
        int2 r = fh[(long)s * 24 + c];
        float2 lo = unpack2(r.x), hi = unpack2(r.y);
        ax += lo.x; ay += lo.y; az += hi.x; aw += hi.y;
    }
    out4[ob] = make_float4(ax * dn, ay * dn, az * dn, aw * dn);
}

// ---------------------------------------------------------------------------
// K5b: pull16 — same aggregation, fp16 packed output (feeds MFMA dual GEMM).
// ---------------------------------------------------------------------------
__global__ __launch_bounds__(384)
void pull16_kernel(const int2* __restrict__ fh, const float* __restrict__ dinv,
                   const int* __restrict__ rowptr, const int* __restrict__ col,
                   int N, int HUB, int2* __restrict__ out16) {
    int c = threadIdx.x;
    int n = blockIdx.x * 16 + threadIdx.y;
    if (n >= N) return;
    long ob = (long)n * 24 + c;
    if (n == HUB) { out16[ob] = make_int2(0, 0); return; }
    int beg = rowptr[n], end = rowptr[n + 1];
    float dn = dinv[n];
    float ax = 0.f, ay = 0.f, az = 0.f, aw = 0.f;
    int e = beg;
    for (; e + 8 <= end; e += 8) {
        int s0 = col[e + 0], s1 = col[e + 1], s2 = col[e + 2], s3 = col[e + 3];
        int s4 = col[e + 4], s5 = col[e + 5], s6 = col[e + 6], s7 = col[e + 7];
        int2 r0 = fh[(long)s0 * 24 + c], r1 = fh[(long)s1 * 24 + c];
        int2 r2 = fh[(long)s2 * 24 + c], r3 = fh[(long)s3 * 24 + c];
        int2 r4 = fh[(long)s4 * 24 + c], r5 = fh[(long)s5 * 24 + c];
        int2 r6 = fh[(long)s6 * 24 + c], r7 = fh[(long)s7 * 24 + c];
        float2 l0 = unpack2(r0.x), h0 = unpack2(r0.y);
        float2 l1 = unpack2(r1.x), h1_ = unpack2(r1.y);
        float2 l2 = unpack2(r2.x), h2 = unpack2(r2.y);
        float2 l3 = unpack2(r3.x), h3 = unpack2(r3.y);
        float2 l4 = unpack2(r4.x), h4 = unpack2(r4.y);
        float2 l5 = unpack2(r5.x), h5 = unpack2(r5.y);
        float2 l6 = unpack2(r6.x), h6 = unpack2(r6.y);
        float2 l7 = unpack2(r7.x), h7 = unpack2(r7.y);
        ax += (l0.x + l1.x) + (l2.x + l3.x) + (l4.x + l5.x) + (l6.x + l7.x);
        ay += (l0.y + l1.y) + (l2.y + l3.y) + (l4.y + l5.y) + (l6.y + l7.y);
        az += (h0.x + h1_.x) + (h2.x + h3.x) + (h4.x + h5.x) + (h6.x + h7.x);
        aw += (h0.y + h1_.y) + (h2.y + h3.y) + (h4.y + h5.y) + (h6.y + h7.y);
    }
    for (; e < end; e++) {
        int s = col[e];
        int2 r = fh[(long)s * 24 + c];
        float2 lo = unpack2(r.x), hi = unpack2(r.y);
        ax += lo.x; ay += lo.y; az += hi.x; aw += hi.y;
    }
    out16[ob] = pack4(ax * dn, ay * dn, az * dn, aw * dn);
}

// ---------------------------------------------------------------------------
// K6: hub row aggregation: dest[0..95] += dinv[HUB]*sum fh[s] (dest fp32,
// pre-zeroed). 256 blocks x 8 streams, LDS reduce, 96 atomics/block.
// ---------------------------------------------------------------------------
__global__ __launch_bounds__(192)
void hub_kernel(const int2* __restrict__ fh, const float* __restrict__ dinv,
                const int* __restrict__ rowptr, const int* __restrict__ col,
                int HUB, float* __restrict__ dest) {
    int c = threadIdx.x;   // 0..23
    int y = threadIdx.y;   // 0..7
    int beg = rowptr[HUB], end = rowptr[HUB + 1];
    int deg = end - beg;
    int nstr = gridDim.x * 8;
    int sid  = blockIdx.x * 8 + y;
    int chunk = (deg + nstr - 1) / nstr;
    int e  = beg + sid * chunk;
    int e1 = min(e + chunk, end);
    float ax = 0.f, ay = 0.f, az = 0.f, aw = 0.f;
    for (; e + 4 <= e1; e += 4) {
        int s0 = col[e + 0], s1 = col[e + 1], s2 = col[e + 2], s3 = col[e + 3];
        int2 r0 = fh[(long)s0 * 24 + c], r1 = fh[(long)s1 * 24 + c];
        int2 r2 = fh[(long)s2 * 24 + c], r3 = fh[(long)s3 * 24 + c];
        float2 l0 = unpack2(r0.x), h0 = unpack2(r0.y);
        float2 l1 = unpack2(r1.x), h1_ = unpack2(r1.y);
        float2 l2 = unpack2(r2.x), h2 = unpack2(r2.y);
        float2 l3 = unpack2(r3.x), h3 = unpack2(r3.y);
        ax += (l0.x + l1.x) + (l2.x + l3.x);
        ay += (l0.y + l1.y) + (l2.y + l3.y);
        az += (h0.x + h1_.x) + (h2.x + h3.x);
        aw += (h0.y + h1_.y) + (h2.y + h3.y);
    }
    for (; e < e1; e++) {
        int s = col[e];
        int2 r = fh[(long)s * 24 + c];
        float2 lo = unpack2(r.x), hi = unpack2(r.y);
        ax += lo.x; ay += lo.y; az += hi.x; aw += hi.y;
    }
    __shared__ float4 red[8][24];
    red[y][c] = make_float4(ax, ay, az, aw);
    __syncthreads();
    if (y == 0) {
        float4 t = red[0][c];
        #pragma unroll
        for (int k = 1; k < 8; k++) {
            float4 u = red[k][c];
            t.x += u.x; t.y += u.y; t.z += u.z; t.w += u.w;
        }
        float dh = dinv[HUB];
        float* o = dest + 4 * c;
        unsafeAtomicAdd(o + 0, t.x * dh);
        unsafeAtomicAdd(o + 1, t.y * dh);
        unsafeAtomicAdd(o + 2, t.z * dh);
        unsafeAtomicAdd(o + 3, t.w * dh);
    }
}

// ---------------------------------------------------------------------------
// K6b: pack_hub — a1h hub row = fp16(hubacc).  1 block x 24 threads.
// ---------------------------------------------------------------------------
__global__ void pack_hub(const float* __restrict__ hubacc, int HUB,
                         int2* __restrict__ a1h16) {
    int c = threadIdx.x;   // 0..23
    if (c < 24)
        a1h16[(long)HUB * 24 + c] = pack4(hubacc[4 * c + 0], hubacc[4 * c + 1],
                                          hubacc[4 * c + 2], hubacc[4 * c + 3]);
}

// ---------------------------------------------------------------------------
// K7: gemm96_h — h1h = fp16(dinv*relu(A@W1+b1)). W staged fp16 in LDS.
// ---------------------------------------------------------------------------
__global__ __launch_bounds__(192)
void gemm96_h(const float* __restrict__ A, const float* __restrict__ W,
              const float* __restrict__ bias, const float* __restrict__ dinv,
              int2* __restrict__ out16, int N) {
    __shared__ __half Wl[FD * FD];       // 18432 B
    __shared__ float As[64 * 100];       // 25600 B
    int t = threadIdx.y * 24 + threadIdx.x;
    {   // stage W fp32 -> fp16
        const float4* W4 = (const float4*)W;
        #pragma unroll 4
        for (int i = t; i < FD * 24; i += 192) {
            float4 w = W4[i];
            *(int2*)&Wl[i * 4] = pack4(w.x, w.y, w.z, w.w);
        }
    }
    int row0 = blockIdx.x * 64;
    int nrows = min(64, N - row0);
    {
        const float4* A4 = (const float4*)(A + (long)row0 * FD);
        for (int i = t; i < nrows * 24; i += 192) {
            int r = i / 24, g = i % 24;
            *(float4*)&As[r * 100 + g * 4] = A4[i];
        }
    }
    __syncthreads();
    int c = threadIdx.x, y = threadIdx.y;
    float acc[8][4];
    #pragma unroll
    for (int j = 0; j < 8; j++)
        #pragma unroll
        for (int i = 0; i < 4; i++) acc[j][i] = 0.f;
    for (int kk = 0; kk < FD; kk += 4) {
        float4 w0 = lds_w4(Wl, kk + 0, 4 * c);
        float4 w1 = lds_w4(Wl, kk + 1, 4 * c);
        float4 w2 = lds_w4(Wl, kk + 2, 4 * c);
        float4 w3 = lds_w4(Wl, kk + 3, 4 * c);
        #pragma unroll
        for (int j = 0; j < 8; j++) {
            float4 a = *(const float4*)&As[(y + 8 * j) * 100 + kk];
            acc[j][0] = fmaf(a.x, w0.x, fmaf(a.y, w1.x, fmaf(a.z, w2.x, fmaf(a.w, w3.x, acc[j][0]))));
            acc[j][1] = fmaf(a.x, w0.y, fmaf(a.y, w1.y, fmaf(a.z, w2.y, fmaf(a.w, w3.y, acc[j][1]))));
            acc[j][2] = fmaf(a.x, w0.z, fmaf(a.y, w1.z, fmaf(a.z, w2.z, fmaf(a.w, w3.z, acc[j][2]))));
            acc[j][3] = fmaf(a.x, w0.w, fmaf(a.y, w1.w, fmaf(a.z, w2.w, fmaf(a.w, w3.w, acc[j][3]))));
        }
    }
    float4 b4 = *(const float4*)&bias[4 * c];
    #pragma unroll
    for (int j = 0; j < 8; j++) {
        int r = y + 8 * j;
        if (r < nrows) {
            float vx = fmaxf(acc[j][0] + b4.x, 0.f);
            float vy = fmaxf(acc[j][1] + b4.y, 0.f);
            float vz = fmaxf(acc[j][2] + b4.z, 0.f);
            float vw = fmaxf(acc[j][3] + b4.w, 0.f);
            float dr = dinv[row0 + r];
            out16[(long)(row0 + r) * 24 + c] = pack4(vx * dr, vy * dr, vz * dr, vw * dr);
        }
    }
}

// ---------------------------------------------------------------------------
// K8: mfma_dual — mu = A@Wa+ba, ls = A@Wb+bb via v_mfma_f32_16x16x32_f16.
// A = a1h fp16 [padded >= N+64 rows][96]. Wta/Wtb = fp16 TRANSPOSED (Wt[n][k]).
// Block = 256 thr = 4 waves; wave handles 16 rows; 6 N-tiles x 2 mats x 3 K.
// Fragment layouts (cdna4 guide, m89-verified C/D):
//   A: lane holds A[m=lane&15][k=(lane>>4)*8 + j]   (16B contiguous load)
//   B: lane holds B[k=(lane>>4)*8+j][n=lane&15] = Wt[n=lane&15][k...] (16B)
//   D: col=lane&15, row=(lane>>4)*4+reg
// ---------------------------------------------------------------------------
__global__ __launch_bounds__(256)
void mfma_dual(const __half* __restrict__ a1h,
               const __half* __restrict__ Wta, const __half* __restrict__ Wtb,
               const float* __restrict__ ba, const float* __restrict__ bb,
               float* __restrict__ mu, float* __restrict__ ls, int N) {
    __shared__ __half WtaL[FD * FD];     // 18432 B
    __shared__ __half WtbL[FD * FD];     // 18432 B
    int t = threadIdx.x;
    {
        const int4* sa = (const int4*)Wta;
        const int4* sb = (const int4*)Wtb;
        int4* da = (int4*)WtaL;
        int4* db = (int4*)WtbL;
        #pragma unroll
        for (int i = t; i < FD * FD / 8; i += 256) { da[i] = sa[i]; db[i] = sb[i]; }
    }
    __syncthreads();
    int wv = t >> 6, lane = t & 63;
    int m = lane & 15, q = lane >> 4;
    long row0 = (long)blockIdx.x * 64 + wv * 16;

    // A fragments for K=96 (3 x 16B loads; a1h padded so over-read is safe)
    const f16x8* arow = (const f16x8*)&a1h[(row0 + m) * FD + q * 8];
    f16x8 A0 = arow[0];   // k in [0,32)
    f16x8 A1 = arow[4];   // k in [32,64)
    f16x8 A2 = arow[8];   // k in [64,96)

    #pragma unroll
    for (int nt = 0; nt < 6; nt++) {
        int n0 = nt * 16;
        const f16x8* brA = (const f16x8*)&WtaL[(n0 + m) * FD + q * 8];
        const f16x8* brB = (const f16x8*)&WtbL[(n0 + m) * FD + q * 8];
        f32x4 acca = {0.f, 0.f, 0.f, 0.f};
        f32x4 accb = {0.f, 0.f, 0.f, 0.f};
        acca = __builtin_amdgcn_mfma_f32_16x16x32_f16(A0, brA[0], acca, 0, 0, 0);
        acca = __builtin_amdgcn_mfma_f32_16x16x32_f16(A1, brA[4], acca, 0, 0, 0);
        acca = __builtin_amdgcn_mfma_f32_16x16x32_f16(A2, brA[8], acca, 0, 0, 0);
        accb = __builtin_amdgcn_mfma_f32_16x16x32_f16(A0, brB[0], accb, 0, 0, 0);
        accb = __builtin_amdgcn_mfma_f32_16x16x32_f16(A1, brB[4], accb, 0, 0, 0);
        accb = __builtin_amdgcn_mfma_f32_16x16x32_f16(A2, brB[8], accb, 0, 0, 0);
        float bva = ba[n0 + m];
        float bvb = bb[n0 + m];
        #pragma unroll
        for (int r = 0; r < 4; r++) {
            long row = row0 + q * 4 + r;
            if (row < N) {
                mu[row * FD + n0 + m] = acca[r] + bva;
                ls[row * FD + n0 + m] = accb[r] + bvb;
            }
        }
    }
}

// ---------------------------------------------------------------------------
// Launch.  (A@X)@W == A@(X@W); gathers on dinv-prescaled fp16 features.
//   xh  = fp16(dinv*x)              -> mu slot, lower 9.6 MB
//   a0  = agg(xh)  (pull+hub)       -> ls slot (fp32)
//   h1h = fp16(dinv*relu(a0@W1+b1)) -> mu slot, upper 9.6 MB  (a0 dead)
//   a1h = fp16 agg(h1h)             -> ws (pull16 + hub->hubacc->pack)
//   mu,ls = MFMA dual-gemm(a1h)     -> mu slot + ls slot (xh,h1h,a0 all dead)
// ws: [counts N][hubacc 96][perm E][bsum 1024][rowptr N+1][col E][dinv N]
//     [Wta 96x96 h][Wtb 96x96 h][a1h (N+64)x96 h]   ~= 17.5 MB  (R1 proved ~19.6 safe)
// ---------------------------------------------------------------------------
extern "C" void kernel_launch(void* const* d_in, const int* in_sizes, int n_in,
                              void* d_out, int out_size, void* d_ws, size_t ws_size,
                              hipStream_t stream) {
    const float* x   = (const float*)d_in[0];
    const float* W1  = (const float*)d_in[1];
    const float* b1  = (const float*)d_in[2];
    const float* W2a = (const float*)d_in[3];
    const float* b2a = (const float*)d_in[4];
    const float* W2b = (const float*)d_in[5];
    const float* b2b = (const float*)d_in[6];
    const int*   ei  = (const int*)d_in[7];

    const int N   = in_sizes[0] / FD;
    const int E   = in_sizes[7] / 2;
    const int HUB = N - 1;
    const int* src = ei;
    const int* dst = ei + E;
    const int NB  = (N + 1023) / 1024;

    int* counts   = (int*)d_ws;                 // N
    float* hubacc = (float*)(counts + N);       // 96
    int* perm     = (int*)(hubacc + FD);        // E
    int* bsum     = perm + E;                   // 1024
    int* rowptr   = bsum + 1024;                // N+1
    int* col      = rowptr + (N + 1);           // E
    float* dinv   = (float*)(col + E);          // N
    uintptr_t p = (uintptr_t)(dinv + N);
    p = (p + 15) & ~(uintptr_t)15;
    __half* Wta = (__half*)p;                   // FD*FD
    __half* Wtb = Wta + FD * FD;                // FD*FD
    __half* a1h = Wtb + FD * FD;                // (N+64)*FD halves

    float* mu_slot = (float*)d_out;
    float* ls_slot = (float*)d_out + (size_t)N * FD;
    int2* xh  = (int2*)mu_slot;                      // 9.6 MB
    int2* h1h = (int2*)mu_slot + (size_t)N * 24;     // next 9.6 MB
    float* a0 = ls_slot;

    // zero counts + hubacc (contiguous)
    hipMemsetAsync(counts, 0, ((size_t)N + FD) * sizeof(int), stream);

    // CSR build (reused by both layers) + weight transpose
    deg_kernel  <<<dim3((E + 255) / 256), dim3(256), 0, stream>>>(dst, E, HUB,
                                                                  counts, perm);
    scan_partial<<<dim3(NB), dim3(1024), 0, stream>>>(counts, N, bsum);
    scan_bsum   <<<dim3(1),  dim3(1024), 0, stream>>>(bsum, NB, rowptr, N);
    scan_apply  <<<dim3(NB), dim3(1024), 0, stream>>>(counts, bsum, N, rowptr, dinv);
    fill_kernel <<<dim3((E + 255) / 256), dim3(256), 0, stream>>>(src, dst, perm,
                                                                  rowptr, E, col);
    convert_kernel<<<dim3((N * 24 + 255) / 256), dim3(256), 0, stream>>>(x, dinv,
                                                                         N, xh);
    wt_kernel<<<dim3((FD * FD + 255) / 256), dim3(256), 0, stream>>>(W2a, W2b,
                                                                     Wta, Wtb);

    dim3 pullB(24, 16);
    int  pullG = (N + 15) / 16;
    dim3 hubB(24, 8);
    int  hubG = 256;
    int  gemmG = (N + 63) / 64;
    dim3 gemmB(24, 8);

    // layer 1
    pull_kernel<<<dim3(pullG), pullB, 0, stream>>>(xh, dinv, rowptr, col, N, HUB, a0);
    hub_kernel <<<dim3(hubG),  hubB, 0, stream>>>(xh, dinv, rowptr, col, HUB,
                                                  a0 + (size_t)HUB * FD);
    gemm96_h   <<<dim3(gemmG), gemmB, 0, stream>>>(a0, W1, b1, dinv, h1h, N);

    // layer 2: fp16 aggregation -> MFMA dual GEMM
    pull16_kernel<<<dim3(pullG), pullB, 0, stream>>>(h1h, dinv, rowptr, col, N, HUB,
                                                     (int2*)a1h);
    hub_kernel   <<<dim3(hubG),  hubB, 0, stream>>>(h1h, dinv, rowptr, col, HUB,
                                                    hubacc);
    pack_hub     <<<dim3(1), dim3(24), 0, stream>>>(hubacc, HUB, (int2*)a1h);
    mfma_dual    <<<dim3(gemmG), dim3(256), 0, stream>>>(a1h, Wta, Wtb, b2a, b2b,
                                                         mu_slot, ls_slot, N);
}